// Round 7
// baseline (463.458 us; speedup 1.0000x reference)
//
#include <hip/hip_runtime.h>
#include <hip/hip_bf16.h>

#define CB 256       // batch
#define CS 200       // seq
#define CH 128       // H
#define CH2 256      // 2H
#define CL 256       // padded scan length
#define CPAD 56
#define CBS (CB*CS)  // 51200 real tokens

typedef __attribute__((ext_vector_type(8))) short bf16x8;
typedef __attribute__((ext_vector_type(4))) float f32x4;

#define SB16 ((long)CBS*16)   // 16-channel chunk stride (token-major)

// ---------------- static device buffers ------------------------------------
// blocked bf16 activations: elem(c,tok) at (c>>4)*SB16 + tok*16 + (c&15)
__device__ __align__(16) __hip_bfloat16 g_cat [(size_t)CBS*256];
__device__ __align__(16) __hip_bfloat16 g_g1  [(size_t)CBS*256];
__device__ __align__(16) __hip_bfloat16 g_xb  [(size_t)CBS*128]; // residual
__device__ __align__(16) __hip_bfloat16 g_h   [(size_t)CBS*512]; // [re|im]
__device__ __align__(16) __hip_bfloat16 g_ffh [(size_t)CBS*512];
__device__ float g_mask[CB*CL];
__device__ float g_gamma2[2*512];
__device__ float g_bincat[2*512];
__device__ float2 g_lam[2*16*128*16];  // [l][ch16][j][dl] -> lambda^{j+1}
// bf16 weights, 16-K-chunk blocked: elem(r,c) at (c>>4)*(N*16) + r*16 + (c&15)
__device__ __align__(16) __hip_bfloat16 g_Wmap  [128*768];
__device__ __align__(16) __hip_bfloat16 g_Wg1   [256*256];
__device__ __align__(16) __hip_bfloat16 g_Wg2   [128*256];
__device__ __align__(16) __hip_bfloat16 g_Wincat[2*512*128];
__device__ __align__(16) __hip_bfloat16 g_Woutcat[2*128*512];
__device__ __align__(16) __hip_bfloat16 g_Wff1  [2*512*128];
__device__ __align__(16) __hip_bfloat16 g_Wff2  [2*128*512];

__device__ __forceinline__ short f2bf(float f){
  unsigned u = __float_as_uint(f);
  unsigned r = (u + 0x7fffu + ((u>>16)&1u)) >> 16;
  return (short)r;
}
__device__ __forceinline__ float bf2f(short s){
  return __uint_as_float(((unsigned)(unsigned short)s) << 16);
}

typedef const __attribute__((address_space(1))) void* gas1;
typedef __attribute__((address_space(3))) void* las3;
__device__ __forceinline__ void gl16(const void* g, void* l){
  __builtin_amdgcn_global_load_lds((gas1)g, (las3)l, 16, 0, 0);
}

// ---------------- merged setup: weights + mask + lambda prep + gather -------
__device__ __forceinline__ void wblk(__hip_bfloat16* dst, int N, int K, int i, float v){
  int r = i / K, c = i - r*K;
  ((short*)dst)[(long)(c>>4)*((long)N*16) + (long)r*16 + (c&15)] = f2bf(v);
}
__global__ void k_setup(const float* __restrict__ W_map, const float* __restrict__ Wg1,
                        const float* __restrict__ Wg2,
                        const float* __restrict__ Win_re, const float* __restrict__ Win_im,
                        const float* __restrict__ Wout_re, const float* __restrict__ Wout_im,
                        const float* __restrict__ Wff1, const float* __restrict__ Wff2,
                        const int* __restrict__ ids,
                        const float* __restrict__ pl,
                        const float* __restrict__ binre, const float* __restrict__ binim,
                        const float* __restrict__ item_emb){
  int bi = blockIdx.x, t = threadIdx.x;
  if (bi < 2816){
    int i = bi*256 + t;
    if (i < 98304){ wblk(g_Wmap, 128, 768, i, W_map[i]); return; }
    i -= 98304;
    if (i < 65536){ wblk(g_Wg1, 256, 256, i, Wg1[i]); return; }
    i -= 65536;
    if (i < 32768){ wblk(g_Wg2, 128, 256, i, Wg2[i]); return; }
    i -= 32768;
    int l = i / 262144; i -= l*262144;
    if (i < 32768){ wblk(g_Wincat + (long)l*65536, 512, 128, i,       Win_re[(long)l*32768 + i]); return; }
    i -= 32768;
    if (i < 32768){ wblk(g_Wincat + (long)l*65536, 512, 128, i+32768, Win_im[(long)l*32768 + i]); return; }
    i -= 32768;
    if (i < 65536){
      int r = i >> 9, c = i & 511;
      float v = (c < 256) ? Wout_re[(long)l*32768 + r*256 + c]
                          : -Wout_im[(long)l*32768 + r*256 + (c-256)];
      wblk(g_Woutcat + (long)l*65536, 128, 512, i, v); return;
    }
    i -= 65536;
    if (i < 65536){ wblk(g_Wff1 + (long)l*65536, 512, 128, i, Wff1[(long)l*65536 + i]); return; }
    i -= 65536;
    wblk(g_Wff2 + (long)l*65536, 128, 512, i, Wff2[(long)l*65536 + i]);
    return;
  }
  if (bi < 3072){
    int b = bi - 2816;
    float m = 0.f;
    if (t >= CPAD) m = (ids[b*CS + (t - CPAD)] > 0) ? 1.f : 0.f;
    g_mask[b*CL + t] = m;
    return;
  }
  if (bi < 3074){
    int l = bi - 3072, d = t;
    float nu = expf(pl[(l*3+0)*CH2 + d]);
    float th = expf(pl[(l*3+1)*CH2 + d]);
    float gm = expf(pl[(l*3+2)*CH2 + d]);
    g_gamma2[l*512 + d] = gm;       g_gamma2[l*512 + d + 256] = gm;
    g_bincat[l*512 + d] = binre[l*256 + d];
    g_bincat[l*512 + d + 256] = binim[l*256 + d];
    float r = expf(-nu);
    float lre = r*cosf(th), lim = r*sinf(th);
    float pr = lre, pi = lim;
    long base = ((long)l*16 + (d>>4))*2048 + (d&15);
    for (int k = 0; k < 128; k++){
      g_lam[base + (long)k*16] = make_float2(pr, pi);
      float nr = pr*lre - pi*lim;
      float ni = pr*lim + pi*lre;
      pr = nr; pi = ni;
    }
    return;
  }
  {
    // item-embedding gather, 16 tokens per block
    int tok = (bi - 3074)*16 + (t>>4);
    int cg = t & 15;
    int id = ids[tok];
    const float* p = item_emb + (size_t)id*128 + cg*8;
    float4 x0 = *(const float4*)p;
    float4 x1 = *(const float4*)(p + 4);
    bf16x8 v;
    v[0]=f2bf(x0.x); v[1]=f2bf(x0.y); v[2]=f2bf(x0.z); v[3]=f2bf(x0.w);
    v[4]=f2bf(x1.x); v[5]=f2bf(x1.y); v[6]=f2bf(x1.z); v[7]=f2bf(x1.w);
    *(bf16x8*)((short*)g_cat + (long)(cg>>1)*SB16 + (long)tok*16 + (cg&1)*8) = v;
  }
}

// ---------------- MFMA GEMM body, BK=64, global_load_lds staging ------------
// TM=128: EPI0 only, 2x2 waves (MF=4,NF=4).
// TM=64:  EPI0 2x2 waves (MF=2,NF=4); EPI1/2/3 4x1 waves (MF=1,NF=8).
// EPI1: LN(v + bias + xb) -> xb.  EPI2: sigmoid-mix-LN0 -> xb.
// EPI3: LN(v + bias + xb) -> f32 outF (final layer).
template<int TM, int ACT, int EPI, bool GATHER, bool COLSCALE>
__device__ __forceinline__ void mgemm_body(
    const short* __restrict__ A, const float* __restrict__ Af32, int ldaF,
    const short* __restrict__ W, long wBlk,
    const float* __restrict__ bias, const float* __restrict__ gamma,
    const int* __restrict__ gidx, short* __restrict__ C,
    long aBlk, int colOff, int K,
    const float* __restrict__ lnG, const float* __restrict__ lnB,
    float* __restrict__ outF)
{
  constexpr int ACH = TM*32;                 // bytes per 16-k A chunk
  __shared__ __align__(16) char lA[TM*128];
  __shared__ __align__(16) char lB[16384];
  constexpr int MF = (EPI==0) ? (TM/32) : 1;
  constexpr int NF = (EPI==0) ? 4 : 8;
  const int t = threadIdx.x;
  const int m0 = blockIdx.x*TM, n0 = blockIdx.y*128;
  const int lane = t & 63, wv = t >> 6;
  const int wr = (EPI==0)?(wv>>1):wv;
  const int wc = (EPI==0)?(wv&1):0;
  const int fr = lane & 15, fq = lane >> 4;
  const int rowB = (EPI==0) ? wr*(TM/2) : wv*16;
  const int colB = wc*64;

  long gr0 = 0, gr1 = 0;
  if (GATHER){ gr0 = gidx[m0 + (t>>3)]; gr1 = gidx[m0 + (t>>3) + 32]; }

  f32x4 acc[MF][NF] = {};

  for (int k0 = 0; k0 < K; k0 += 64){
    if (TM == 128){
      #pragma unroll
      for (int cc = 0; cc < 4; cc++){
        const short* gp = A + (long)((k0>>4)+cc)*aBlk + (long)(m0 + wv*32)*16 + (lane<<3);
        gl16(gp, lA + cc*4096 + wv*1024);
      }
      #pragma unroll
      for (int cc = 0; cc < 4; cc++){
        const short* gp = W + (long)((k0>>4)+cc)*wBlk + (long)(n0 + wv*32)*16 + (lane<<3);
        gl16(gp, lB + cc*4096 + wv*1024);
      }
    } else {
      if (GATHER){
        #pragma unroll
        for (int rep = 0; rep < 2; rep++){
          int slot = t + rep*256;
          int row = slot>>3, cc = (slot>>1)&3, half = slot&1;
          long ar = rep ? gr1 : gr0;
          const float* p = Af32 + ar*(long)ldaF + k0 + cc*16 + half*8;
          float4 x0 = *(const float4*)p;
          float4 x1 = *(const float4*)(p + 4);
          bf16x8 v;
          v[0]=f2bf(x0.x); v[1]=f2bf(x0.y); v[2]=f2bf(x0.z); v[3]=f2bf(x0.w);
          v[4]=f2bf(x1.x); v[5]=f2bf(x1.y); v[6]=f2bf(x1.z); v[7]=f2bf(x1.w);
          *(bf16x8*)(lA + cc*2048 + row*32 + half*16) = v;
        }
      } else {
        #pragma unroll
        for (int p = 0; p < 2; p++){
          const short* gp = A + (long)((k0>>4)+wv)*aBlk + (long)(m0 + p*32 + (lane>>1))*16 + (lane&1)*8;
          gl16(gp, lA + wv*2048 + p*1024);
        }
      }
      #pragma unroll
      for (int p = 0; p < 4; p++){
        const short* gp = W + (long)((k0>>4)+wv)*wBlk + (long)(n0 + p*32 + (lane>>1))*16 + (lane&1)*8;
        gl16(gp, lB + wv*4096 + p*1024);
      }
    }
    __syncthreads();
    #pragma unroll
    for (int s = 0; s < 2; s++){
      const int cc = s*2 + (fq>>1);
      bf16x8 af[MF], bw[NF];
      #pragma unroll
      for (int m = 0; m < MF; m++)
        af[m] = *(const bf16x8*)(lA + cc*ACH + (rowB + m*16 + fr)*32 + (fq&1)*16);
      #pragma unroll
      for (int n = 0; n < NF; n++)
        bw[n] = *(const bf16x8*)(lB + cc*4096 + (colB + n*16 + fr)*32 + (fq&1)*16);
      #pragma unroll
      for (int m = 0; m < MF; m++)
        #pragma unroll
        for (int n = 0; n < NF; n++)
          acc[m][n] = __builtin_amdgcn_mfma_f32_16x16x32_bf16(af[m], bw[n], acc[m][n], 0, 0, 0);
    }
    __syncthreads();
  }

  if (EPI == 0){
    #pragma unroll
    for (int m = 0; m < MF; m++){
      #pragma unroll
      for (int j = 0; j < 4; j++){
        long row = m0 + rowB + m*16 + fq*4 + j;
        #pragma unroll
        for (int n = 0; n < NF; n++){
          int colL = n0 + colB + n*16 + fr;
          float v = acc[m][n][j] + bias[colL];
          if (COLSCALE) v *= gamma[colL];
          if (ACT == 1) v = 0.5f * v * (1.0f + erff(v * 0.70710678118654752f));
          int colS = colL + colOff;
          C[(long)(colS>>4)*SB16 + row*16 + (colS&15)] = f2bf(v);
        }
      }
    }
  } else {
    #pragma unroll
    for (int j = 0; j < 4; j++){
      int rt = rowB + fq*4 + j;
      long tok = m0 + rt;
      float vv[NF];
      float s1 = 0.f, s2 = 0.f;
      #pragma unroll
      for (int n = 0; n < NF; n++){
        int col = n*16 + fr;
        float v = acc[0][n][j] + bias[col];
        if (EPI == 2){
          v = 1.0f / (1.0f + expf(-v));
          float idv = bf2f(((const short*)g_cat)[(long)n*SB16 + tok*16 + fr]);
          float lmv = bf2f(((const short*)g_cat)[(long)(n+8)*SB16 + tok*16 + fr]);
          v = v*idv + (1.0f - v)*lmv;
        } else {
          v += bf2f(((const short*)g_xb)[(long)n*SB16 + tok*16 + fr]);
        }
        vv[n] = v; s1 += v; s2 += v*v;
      }
      #pragma unroll
      for (int off = 1; off < 16; off <<= 1){
        s1 += __shfl_xor(s1, off); s2 += __shfl_xor(s2, off);
      }
      float mu = s1 * (1.f/128.f);
      float var = s2 * (1.f/128.f) - mu*mu;
      float rstd = rsqrtf(var + 1e-12f);
      #pragma unroll
      for (int n = 0; n < NF; n++){
        int col = n*16 + fr;
        float o = (vv[n] - mu)*rstd*lnG[col] + lnB[col];
        if (EPI == 3)
          outF[tok*128 + col] = o;
        else
          ((short*)g_xb)[(long)n*SB16 + tok*16 + fr] = f2bf(o);
      }
    }
  }
}

// ---------------- named GEMM wrappers ---------------------------------------
__global__ __launch_bounds__(256) void kg_llm(const float* llm_emb, const float* b_map, const int* ids){
  mgemm_body<64,0,0,true,false>(nullptr, llm_emb, 768, (const short*)g_Wmap, 128L*16,
                                b_map, nullptr, ids, (short*)g_cat, 0, 128, 768, nullptr, nullptr, nullptr);
}
__global__ __launch_bounds__(256) void kg_g1(const float* bg1){
  mgemm_body<64,1,0,false,false>((const short*)g_cat, nullptr, 0, (const short*)g_Wg1, 256L*16,
                                 bg1, nullptr, nullptr, (short*)g_g1, SB16, 0, 256, nullptr, nullptr, nullptr);
}
__global__ __launch_bounds__(256) void kg_gate(const float* bg2, const float* ln0g, const float* ln0b){
  mgemm_body<64,0,2,false,false>((const short*)g_g1, nullptr, 0, (const short*)g_Wg2, 128L*16,
                                 bg2, nullptr, nullptr, nullptr, SB16, 0, 256, ln0g, ln0b, nullptr);
}
__global__ __launch_bounds__(256) void kg_h(int l){
  mgemm_body<128,0,0,false,true>((const short*)g_xb, nullptr, 0,
                                 (const short*)g_Wincat + (long)l*65536, 512L*16,
                                 g_bincat + l*512, g_gamma2 + l*512, nullptr, (short*)g_h,
                                 SB16, 0, 128, nullptr, nullptr, nullptr);
}
__global__ __launch_bounds__(256) void kg_out(int l, const float* bout, const float* g, const float* b){
  mgemm_body<64,0,1,false,false>((const short*)g_h, nullptr, 0,
                                 (const short*)g_Woutcat + (long)l*65536, 128L*16,
                                 bout, nullptr, nullptr, nullptr, SB16, 0, 512, g, b, nullptr);
}
__global__ __launch_bounds__(256) void kg_ff1(int l, const float* bff1){
  mgemm_body<128,1,0,false,false>((const short*)g_xb, nullptr, 0,
                                  (const short*)g_Wff1 + (long)l*65536, 512L*16,
                                  bff1, nullptr, nullptr, (short*)g_ffh, SB16, 0, 128, nullptr, nullptr, nullptr);
}
__global__ __launch_bounds__(256) void kg_ff2(int l, const float* bff2, const float* g, const float* b){
  mgemm_body<64,0,1,false,false>((const short*)g_ffh, nullptr, 0,
                                 (const short*)g_Wff2 + (long)l*65536, 128L*16,
                                 bff2, nullptr, nullptr, nullptr, SB16, 0, 512, g, b, nullptr);
}
__global__ __launch_bounds__(256) void kg_ff2o(int l, const float* bff2, const float* g, const float* b,
                                               float* outF){
  mgemm_body<64,0,3,false,false>((const short*)g_ffh, nullptr, 0,
                                 (const short*)g_Wff2 + (long)l*65536, 128L*16,
                                 bff2, nullptr, nullptr, nullptr, SB16, 0, 512, g, b, outF);
}

// ---------------- register-resident blocked LRU scan ------------------------
// Thread (dl, g) owns positions t = g+16k, k=0..15, in registers.
// Per level: boundary owners write h[p]*m[p] to LDS carry; targets FMA
// lambda^{t-p} * carry from registers. Exact reference merge semantics.
__global__ __launch_bounds__(256) void k_scan(int l){
  __shared__ __align__(16) float2 cbuf[128*17]; // padded stride 17
  const int b = blockIdx.y, ch = blockIdx.x;    // ch 0..15
  const int tid = threadIdx.x, dl = tid & 15, g = tid >> 4;
  short* Hre = (short*)g_h + (long)ch*SB16 + (long)b*CS*16;
  short* Him = (short*)g_h + (long)(ch+16)*SB16 + (long)b*CS*16;
  const float2* lam = g_lam + ((long)l*16 + ch)*2048;  // [j][16dl]

  float2 P[8];
  #pragma unroll
  for (int q = 0; q < 8; q++) P[q] = lam[(g + 16*q)*16 + dl];
  float2 S1 = lam[0*16 + dl];
  float2 S2 = lam[(g&1)*16 + dl];
  float2 S3 = lam[(g&3)*16 + dl];
  float2 S4 = lam[(g&7)*16 + dl];

  unsigned mb = 0;
  #pragma unroll
  for (int k = 0; k < 16; k++){
    int t = g + 16*k;
    mb |= (g_mask[b*CL + t] != 0.f ? 1u : 0u) << k;
  }

  float2 h[16];
  #pragma unroll
  for (int k = 0; k < 16; k++){
    int t = g + 16*k;
    if (t >= CPAD){
      int r = t - CPAD;
      h[k].x = bf2f(Hre[r*16 + dl]);
      h[k].y = bf2f(Him[r*16 + dl]);
    } else { h[k].x = 0.f; h[k].y = 0.f; }
  }

  #pragma unroll
  for (int i = 1; i <= 8; i++){
    const int hl = 1 << (i-1);
    #pragma unroll
    for (int k = 0; k < 16; k++){
      int t = g + 16*k;
      if ((t & (2*hl-1)) == hl-1){
        float m = ((mb >> k) & 1) ? 1.f : 0.f;
        cbuf[(t>>i)*17 + dl] = make_float2(h[k].x*m, h[k].y*m);
      }
    }
    __syncthreads();
    #pragma unroll
    for (int k = 0; k < 16; k++){
      int t = g + 16*k;
      if ((t >> (i-1)) & 1){
        float2 cc = cbuf[(t>>i)*17 + dl];
        float2 L = (i==1)?S1 : (i==2)?S2 : (i==3)?S3 : (i==4)?S4 :
                   (i==5)?P[0] : (i==6)?P[k&1] : (i==7)?P[k&3] : P[k&7];
        h[k].x += L.x*cc.x - L.y*cc.y;
        h[k].y += L.x*cc.y + L.y*cc.x;
      }
    }
    __syncthreads();
  }

  #pragma unroll
  for (int k = 0; k < 16; k++){
    int t = g + 16*k;
    if (t >= CPAD){
      int r = t - CPAD;
      Hre[r*16 + dl] = f2bf(h[k].x);
      Him[r*16 + dl] = f2bf(h[k].y);
    }
  }
}

// ---------------------------------------------------------------------------
extern "C" void kernel_launch(void* const* d_in, const int* in_sizes, int n_in,
                              void* d_out, int out_size, void* d_ws, size_t ws_size,
                              hipStream_t stream) {
  const int*   ids       = (const int*)  d_in[0];
  const float* item_emb  = (const float*)d_in[1];
  const float* llm_emb   = (const float*)d_in[2];
  const float* W_map     = (const float*)d_in[3];
  const float* b_map     = (const float*)d_in[4];
  const float* Wg1       = (const float*)d_in[5];
  const float* bg1       = (const float*)d_in[6];
  const float* Wg2       = (const float*)d_in[7];
  const float* bg2       = (const float*)d_in[8];
  const float* ln0_g     = (const float*)d_in[9];
  const float* ln0_b     = (const float*)d_in[10];
  const float* params_log= (const float*)d_in[11];
  const float* Win_re    = (const float*)d_in[12];
  const float* Win_im    = (const float*)d_in[13];
  const float* bin_re    = (const float*)d_in[14];
  const float* bin_im    = (const float*)d_in[15];
  const float* Wout_re   = (const float*)d_in[16];
  const float* Wout_im   = (const float*)d_in[17];
  const float* bout_re   = (const float*)d_in[18];
  const float* ln1_g     = (const float*)d_in[20];
  const float* ln1_b     = (const float*)d_in[21];
  const float* Wff1      = (const float*)d_in[22];
  const float* bff1      = (const float*)d_in[23];
  const float* Wff2      = (const float*)d_in[24];
  const float* bff2      = (const float*)d_in[25];
  const float* ln2_g     = (const float*)d_in[26];
  const float* ln2_b     = (const float*)d_in[27];
  float* out = (float*)d_out;

  dim3 blk(256);

  k_setup<<<6274, blk, 0, stream>>>(W_map, Wg1, Wg2, Win_re, Win_im,
                                    Wout_re, Wout_im, Wff1, Wff2,
                                    ids, params_log, bin_re, bin_im, item_emb);

  kg_llm <<<dim3(800,1), blk, 0, stream>>>(llm_emb, b_map, ids);
  kg_g1  <<<dim3(800,2), blk, 0, stream>>>(bg1);
  kg_gate<<<dim3(800,1), blk, 0, stream>>>(bg2, ln0_g, ln0_b);

  for (int l = 0; l < 2; l++){
    kg_h  <<<dim3(400,4), blk, 0, stream>>>(l);
    k_scan<<<dim3(16,CB), blk, 0, stream>>>(l);
    kg_out<<<dim3(800,1), blk, 0, stream>>>(l, bout_re + l*128, ln1_g + l*128, ln1_b + l*128);
    kg_ff1<<<dim3(400,4), blk, 0, stream>>>(l, bff1 + l*512);
    if (l == 0)
      kg_ff2 <<<dim3(800,1), blk, 0, stream>>>(l, bff2 + l*128, ln2_g + l*128, ln2_b + l*128);
    else
      kg_ff2o<<<dim3(800,1), blk, 0, stream>>>(l, bff2 + l*128, ln2_g + l*128, ln2_b + l*128, out);
  }
}

// Round 11
// 418.362 us; speedup vs baseline: 1.1078x; 1.1078x over previous
//
#include <hip/hip_runtime.h>
#include <hip/hip_bf16.h>

#define CB 256       // batch
#define CS 200       // seq
#define CH 128       // H
#define CH2 256      // 2H
#define CL 256       // padded scan length
#define CPAD 56
#define CBS (CB*CS)  // 51200 real tokens

typedef __attribute__((ext_vector_type(8))) short bf16x8;
typedef __attribute__((ext_vector_type(4))) float f32x4;

#define SB16 ((long)CBS*16)   // 16-channel chunk stride (token-major)

// ---------------- static device buffers ------------------------------------
// blocked bf16 activations: elem(c,tok) at (c>>4)*SB16 + tok*16 + (c&15)
__device__ __align__(16) __hip_bfloat16 g_cat [(size_t)CBS*256];
__device__ __align__(16) __hip_bfloat16 g_g1  [(size_t)CBS*256];
__device__ __align__(16) __hip_bfloat16 g_xb  [(size_t)CBS*128]; // residual
__device__ __align__(16) __hip_bfloat16 g_h   [(size_t)CBS*512]; // [re|im]
__device__ __align__(16) __hip_bfloat16 g_ffh [(size_t)CBS*512];
__device__ float g_mask[CB*CL];
__device__ float g_gamma2[2*512];
__device__ float g_bincat[2*512];
__device__ float2 g_lam[2*16*128*16];  // [l][ch16][j][dl] -> lambda^{j+1}
// bf16 weights, 16-K-chunk blocked: elem(r,c) at (c>>4)*(N*16) + r*16 + (c&15)
__device__ __align__(16) __hip_bfloat16 g_Wmap  [128*768];
__device__ __align__(16) __hip_bfloat16 g_Wg1   [256*256];
__device__ __align__(16) __hip_bfloat16 g_Wg2   [128*256];
__device__ __align__(16) __hip_bfloat16 g_Wincat[2*512*128];
__device__ __align__(16) __hip_bfloat16 g_Woutcat[2*128*512];
__device__ __align__(16) __hip_bfloat16 g_Wff1  [2*512*128];
__device__ __align__(16) __hip_bfloat16 g_Wff2  [2*128*512];

__device__ __forceinline__ short f2bf(float f){
  unsigned u = __float_as_uint(f);
  unsigned r = (u + 0x7fffu + ((u>>16)&1u)) >> 16;
  return (short)r;
}
__device__ __forceinline__ float bf2f(short s){
  return __uint_as_float(((unsigned)(unsigned short)s) << 16);
}

typedef const __attribute__((address_space(1))) void* gas1;
typedef __attribute__((address_space(3))) void* las3;
__device__ __forceinline__ void gl16(const void* g, void* l){
  __builtin_amdgcn_global_load_lds((gas1)g, (las3)l, 16, 0, 0);
}

// ---------------- merged setup: weights + mask + lambda prep + gather -------
__device__ __forceinline__ void wblk(__hip_bfloat16* dst, int N, int K, int i, float v){
  int r = i / K, c = i - r*K;
  ((short*)dst)[(long)(c>>4)*((long)N*16) + (long)r*16 + (c&15)] = f2bf(v);
}
__global__ void k_setup(const float* __restrict__ W_map, const float* __restrict__ Wg1,
                        const float* __restrict__ Wg2,
                        const float* __restrict__ Win_re, const float* __restrict__ Win_im,
                        const float* __restrict__ Wout_re, const float* __restrict__ Wout_im,
                        const float* __restrict__ Wff1, const float* __restrict__ Wff2,
                        const int* __restrict__ ids,
                        const float* __restrict__ pl,
                        const float* __restrict__ binre, const float* __restrict__ binim,
                        const float* __restrict__ item_emb){
  int bi = blockIdx.x, t = threadIdx.x;
  if (bi < 2816){
    int i = bi*256 + t;
    if (i < 98304){ wblk(g_Wmap, 128, 768, i, W_map[i]); return; }
    i -= 98304;
    if (i < 65536){ wblk(g_Wg1, 256, 256, i, Wg1[i]); return; }
    i -= 65536;
    if (i < 32768){ wblk(g_Wg2, 128, 256, i, Wg2[i]); return; }
    i -= 32768;
    int l = i / 262144; i -= l*262144;
    if (i < 32768){ wblk(g_Wincat + (long)l*65536, 512, 128, i,       Win_re[(long)l*32768 + i]); return; }
    i -= 32768;
    if (i < 32768){ wblk(g_Wincat + (long)l*65536, 512, 128, i+32768, Win_im[(long)l*32768 + i]); return; }
    i -= 32768;
    if (i < 65536){
      int r = i >> 9, c = i & 511;
      float v = (c < 256) ? Wout_re[(long)l*32768 + r*256 + c]
                          : -Wout_im[(long)l*32768 + r*256 + (c-256)];
      wblk(g_Woutcat + (long)l*65536, 128, 512, i, v); return;
    }
    i -= 65536;
    if (i < 65536){ wblk(g_Wff1 + (long)l*65536, 512, 128, i, Wff1[(long)l*65536 + i]); return; }
    i -= 65536;
    wblk(g_Wff2 + (long)l*65536, 128, 512, i, Wff2[(long)l*65536 + i]);
    return;
  }
  if (bi < 3072){
    int b = bi - 2816;
    float m = 0.f;
    if (t >= CPAD) m = (ids[b*CS + (t - CPAD)] > 0) ? 1.f : 0.f;
    g_mask[b*CL + t] = m;
    return;
  }
  if (bi < 3074){
    int l = bi - 3072, d = t;
    float nu = expf(pl[(l*3+0)*CH2 + d]);
    float th = expf(pl[(l*3+1)*CH2 + d]);
    float gm = expf(pl[(l*3+2)*CH2 + d]);
    g_gamma2[l*512 + d] = gm;       g_gamma2[l*512 + d + 256] = gm;
    g_bincat[l*512 + d] = binre[l*256 + d];
    g_bincat[l*512 + d + 256] = binim[l*256 + d];
    float r = expf(-nu);
    float lre = r*cosf(th), lim = r*sinf(th);
    float pr = lre, pi = lim;
    long base = ((long)l*16 + (d>>4))*2048 + (d&15);
    for (int k = 0; k < 128; k++){
      g_lam[base + (long)k*16] = make_float2(pr, pi);
      float nr = pr*lre - pi*lim;
      float ni = pr*lim + pi*lre;
      pr = nr; pi = ni;
    }
    return;
  }
  {
    // item-embedding gather, 16 tokens per block
    int tok = (bi - 3074)*16 + (t>>4);
    int cg = t & 15;
    int id = ids[tok];
    const float* p = item_emb + (size_t)id*128 + cg*8;
    float4 x0 = *(const float4*)p;
    float4 x1 = *(const float4*)(p + 4);
    bf16x8 v;
    v[0]=f2bf(x0.x); v[1]=f2bf(x0.y); v[2]=f2bf(x0.z); v[3]=f2bf(x0.w);
    v[4]=f2bf(x1.x); v[5]=f2bf(x1.y); v[6]=f2bf(x1.z); v[7]=f2bf(x1.w);
    *(bf16x8*)((short*)g_cat + (long)(cg>>1)*SB16 + (long)tok*16 + (cg&1)*8) = v;
  }
}

// ---------------- MFMA GEMM body, BK=64, global_load_lds staging (r6) -------
// TM=128: EPI0, 2x2 waves (MF=4,NF=4).  TM=64: EPI0 2x2 (MF=2,NF=4);
// EPI1/2/3 4x1 waves (MF=1,NF=8): EPI1 LN(v+bias+xb)->xb;
// EPI2 sigmoid-mix-LN0->xb; EPI3 LN(v+bias+xb)->f32 out.
template<int TM, int ACT, int EPI, bool GATHER, bool COLSCALE>
__device__ __forceinline__ void mgemm_body(
    const short* __restrict__ A, const float* __restrict__ Af32, int ldaF,
    const short* __restrict__ W, long wBlk,
    const float* __restrict__ bias, const float* __restrict__ gamma,
    const int* __restrict__ gidx, short* __restrict__ C,
    long aBlk, int colOff, int K,
    const float* __restrict__ lnG, const float* __restrict__ lnB,
    float* __restrict__ outF)
{
  constexpr int ACH = TM*32;                 // bytes per 16-k A chunk
  __shared__ __align__(16) char lA[TM*128];
  __shared__ __align__(16) char lB[16384];
  constexpr int MF = (EPI==0) ? (TM/32) : 1;
  constexpr int NF = (EPI==0) ? 4 : 8;
  const int t = threadIdx.x;
  const int m0 = blockIdx.x*TM, n0 = blockIdx.y*128;
  const int lane = t & 63, wv = t >> 6;
  const int wr = (EPI==0)?(wv>>1):wv;
  const int wc = (EPI==0)?(wv&1):0;
  const int fr = lane & 15, fq = lane >> 4;
  const int rowB = (EPI==0) ? wr*(TM/2) : wv*16;
  const int colB = wc*64;

  long gr0 = 0, gr1 = 0;
  if (GATHER){ gr0 = gidx[m0 + (t>>3)]; gr1 = gidx[m0 + (t>>3) + 32]; }

  f32x4 acc[MF][NF] = {};

  for (int k0 = 0; k0 < K; k0 += 64){
    if (TM == 128){
      #pragma unroll
      for (int cc = 0; cc < 4; cc++){
        const short* gp = A + (long)((k0>>4)+cc)*aBlk + (long)(m0 + wv*32)*16 + (lane<<3);
        gl16(gp, lA + cc*4096 + wv*1024);
      }
      #pragma unroll
      for (int cc = 0; cc < 4; cc++){
        const short* gp = W + (long)((k0>>4)+cc)*wBlk + (long)(n0 + wv*32)*16 + (lane<<3);
        gl16(gp, lB + cc*4096 + wv*1024);
      }
    } else {
      if (GATHER){
        #pragma unroll
        for (int rep = 0; rep < 2; rep++){
          int slot = t + rep*256;
          int row = slot>>3, cc = (slot>>1)&3, half = slot&1;
          long ar = rep ? gr1 : gr0;
          const float* p = Af32 + ar*(long)ldaF + k0 + cc*16 + half*8;
          float4 x0 = *(const float4*)p;
          float4 x1 = *(const float4*)(p + 4);
          bf16x8 v;
          v[0]=f2bf(x0.x); v[1]=f2bf(x0.y); v[2]=f2bf(x0.z); v[3]=f2bf(x0.w);
          v[4]=f2bf(x1.x); v[5]=f2bf(x1.y); v[6]=f2bf(x1.z); v[7]=f2bf(x1.w);
          *(bf16x8*)(lA + cc*2048 + row*32 + half*16) = v;
        }
      } else {
        #pragma unroll
        for (int p = 0; p < 2; p++){
          const short* gp = A + (long)((k0>>4)+wv)*aBlk + (long)(m0 + p*32 + (lane>>1))*16 + (lane&1)*8;
          gl16(gp, lA + wv*2048 + p*1024);
        }
      }
      #pragma unroll
      for (int p = 0; p < 4; p++){
        const short* gp = W + (long)((k0>>4)+wv)*wBlk + (long)(n0 + p*32 + (lane>>1))*16 + (lane&1)*8;
        gl16(gp, lB + wv*4096 + p*1024);
      }
    }
    __syncthreads();
    #pragma unroll
    for (int s = 0; s < 2; s++){
      const int cc = s*2 + (fq>>1);
      bf16x8 af[MF], bw[NF];
      #pragma unroll
      for (int m = 0; m < MF; m++)
        af[m] = *(const bf16x8*)(lA + cc*ACH + (rowB + m*16 + fr)*32 + (fq&1)*16);
      #pragma unroll
      for (int n = 0; n < NF; n++)
        bw[n] = *(const bf16x8*)(lB + cc*4096 + (colB + n*16 + fr)*32 + (fq&1)*16);
      #pragma unroll
      for (int m = 0; m < MF; m++)
        #pragma unroll
        for (int n = 0; n < NF; n++)
          acc[m][n] = __builtin_amdgcn_mfma_f32_16x16x32_bf16(af[m], bw[n], acc[m][n], 0, 0, 0);
    }
    __syncthreads();
  }

  if (EPI == 0){
    #pragma unroll
    for (int m = 0; m < MF; m++){
      #pragma unroll
      for (int j = 0; j < 4; j++){
        long row = m0 + rowB + m*16 + fq*4 + j;
        #pragma unroll
        for (int n = 0; n < NF; n++){
          int colL = n0 + colB + n*16 + fr;
          float v = acc[m][n][j] + bias[colL];
          if (COLSCALE) v *= gamma[colL];
          if (ACT == 1) v = 0.5f * v * (1.0f + erff(v * 0.70710678118654752f));
          int colS = colL + colOff;
          C[(long)(colS>>4)*SB16 + row*16 + (colS&15)] = f2bf(v);
        }
      }
    }
  } else {
    #pragma unroll
    for (int j = 0; j < 4; j++){
      int rt = rowB + fq*4 + j;
      long tok = m0 + rt;
      float vv[NF];
      float s1 = 0.f, s2 = 0.f;
      #pragma unroll
      for (int n = 0; n < NF; n++){
        int col = n*16 + fr;
        float v = acc[0][n][j] + bias[col];
        if (EPI == 2){
          v = 1.0f / (1.0f + expf(-v));
          float idv = bf2f(((const short*)g_cat)[(long)n*SB16 + tok*16 + fr]);
          float lmv = bf2f(((const short*)g_cat)[(long)(n+8)*SB16 + tok*16 + fr]);
          v = v*idv + (1.0f - v)*lmv;
        } else {
          v += bf2f(((const short*)g_xb)[(long)n*SB16 + tok*16 + fr]);
        }
        vv[n] = v; s1 += v; s2 += v*v;
      }
      #pragma unroll
      for (int off = 1; off < 16; off <<= 1){
        s1 += __shfl_xor(s1, off); s2 += __shfl_xor(s2, off);
      }
      float mu = s1 * (1.f/128.f);
      float var = s2 * (1.f/128.f) - mu*mu;
      float rstd = rsqrtf(var + 1e-12f);
      #pragma unroll
      for (int n = 0; n < NF; n++){
        int col = n*16 + fr;
        float o = (vv[n] - mu)*rstd*lnG[col] + lnB[col];
        if (EPI == 3)
          outF[tok*128 + col] = o;
        else
          ((short*)g_xb)[(long)n*SB16 + tok*16 + fr] = f2bf(o);
      }
    }
  }
}

// ---------------- named single-GEMM wrappers --------------------------------
__global__ __launch_bounds__(256) void kg_llm(const float* llm_emb, const float* b_map, const int* ids){
  mgemm_body<64,0,0,true,false>(nullptr, llm_emb, 768, (const short*)g_Wmap, 128L*16,
                                b_map, nullptr, ids, (short*)g_cat, 0, 128, 768, nullptr, nullptr, nullptr);
}
__global__ __launch_bounds__(256) void kg_g1(const float* bg1){
  mgemm_body<64,1,0,false,false>((const short*)g_cat, nullptr, 0, (const short*)g_Wg1, 256L*16,
                                 bg1, nullptr, nullptr, (short*)g_g1, SB16, 0, 256, nullptr, nullptr, nullptr);
}
__global__ __launch_bounds__(256) void kg_gate(const float* bg2, const float* ln0g, const float* ln0b){
  mgemm_body<64,0,2,false,false>((const short*)g_g1, nullptr, 0, (const short*)g_Wg2, 128L*16,
                                 bg2, nullptr, nullptr, nullptr, SB16, 0, 256, ln0g, ln0b, nullptr);
}
__global__ __launch_bounds__(256) void kg_h(int l){
  mgemm_body<128,0,0,false,true>((const short*)g_xb, nullptr, 0,
                                 (const short*)g_Wincat + (long)l*65536, 512L*16,
                                 g_bincat + l*512, g_gamma2 + l*512, nullptr, (short*)g_h,
                                 SB16, 0, 128, nullptr, nullptr, nullptr);
}
__global__ __launch_bounds__(256) void kg_out(int l, const float* bout, const float* g, const float* b){
  mgemm_body<64,0,1,false,false>((const short*)g_h, nullptr, 0,
                                 (const short*)g_Woutcat + (long)l*65536, 128L*16,
                                 bout, nullptr, nullptr, nullptr, SB16, 0, 512, g, b, nullptr);
}
__global__ __launch_bounds__(256) void kg_ff1(int l, const float* bff1){
  mgemm_body<128,1,0,false,false>((const short*)g_xb, nullptr, 0,
                                  (const short*)g_Wff1 + (long)l*65536, 512L*16,
                                  bff1, nullptr, nullptr, (short*)g_ffh, SB16, 0, 128, nullptr, nullptr, nullptr);
}
__global__ __launch_bounds__(256) void kg_ff2(int l, const float* bff2, const float* g, const float* b){
  mgemm_body<64,0,1,false,false>((const short*)g_ffh, nullptr, 0,
                                 (const short*)g_Wff2 + (long)l*65536, 128L*16,
                                 bff2, nullptr, nullptr, nullptr, SB16, 0, 512, g, b, nullptr);
}
__global__ __launch_bounds__(256) void kg_ff2o(int l, const float* bff2, const float* g, const float* b,
                                               float* outF){
  mgemm_body<64,0,3,false,false>((const short*)g_ffh, nullptr, 0,
                                 (const short*)g_Wff2 + (long)l*65536, 128L*16,
                                 bff2, nullptr, nullptr, nullptr, SB16, 0, 512, g, b, outF);
}

// ---------------- blocked LRU scan (r6 LDS version, proven) -----------------
__global__ __launch_bounds__(256) void k_scan(int l){
  __shared__ __align__(16) float sre[CL*16];
  __shared__ __align__(16) float sim[CL*16];
  __shared__ float smask[CL];
  int b = blockIdx.y, ch = blockIdx.x;  // ch 0..15
  int tid = threadIdx.x;
  short* Hre = (short*)g_h + (long)ch*SB16 + (long)b*CS*16;
  short* Him = (short*)g_h + (long)(ch+16)*SB16 + (long)b*CS*16;
  smask[tid] = g_mask[b*CL + tid];
  for (int q = tid; q < 224; q += 256){    // zero pad rows 0..55
    ((float4*)sre)[q] = make_float4(0.f,0.f,0.f,0.f);
    ((float4*)sim)[q] = make_float4(0.f,0.f,0.f,0.f);
  }
  for (int q = tid; q < 400; q += 256){    // 200 tokens * 16 / 8
    bf16x8 r8 = ((const bf16x8*)Hre)[q];
    bf16x8 i8 = ((const bf16x8*)Him)[q];
    int base = 896 + q*8;
    #pragma unroll
    for (int k = 0; k < 8; k++){ sre[base+k] = bf2f(r8[k]); sim[base+k] = bf2f(i8[k]); }
  }
  __syncthreads();
  const float2* lam = g_lam + ((long)l*16 + ch)*2048;
  const int dl = tid & 15, u0 = tid >> 4;
  for (int i = 1; i <= 8; i++){
    int hl = 1 << (i-1);
    #pragma unroll
    for (int k = 0; k < 8; k++){
      int u = u0 + k*16;
      int blkI = u >> (i-1), j = u & (hl-1);
      int p = (blkI << i) + hl - 1;
      int tt = p + 1 + j;
      float mv = smask[p];
      float2 L = lam[j*16 + dl];
      float hr = sre[p*16+dl], hi = sim[p*16+dl];
      sre[tt*16+dl] += (L.x*hr - L.y*hi) * mv;
      sim[tt*16+dl] += (L.x*hi + L.y*hr) * mv;
    }
    __syncthreads();
  }
  for (int q = tid; q < 400; q += 256){
    int base = 896 + q*8;
    bf16x8 r8, i8;
    #pragma unroll
    for (int k = 0; k < 8; k++){ r8[k] = f2bf(sre[base+k]); i8[k] = f2bf(sim[base+k]); }
    ((bf16x8*)Hre)[q] = r8;
    ((bf16x8*)Him)[q] = i8;
  }
}

// ---------------------------------------------------------------------------
extern "C" void kernel_launch(void* const* d_in, const int* in_sizes, int n_in,
                              void* d_out, int out_size, void* d_ws, size_t ws_size,
                              hipStream_t stream) {
  const int*   ids       = (const int*)  d_in[0];
  const float* item_emb  = (const float*)d_in[1];
  const float* llm_emb   = (const float*)d_in[2];
  const float* W_map     = (const float*)d_in[3];
  const float* b_map     = (const float*)d_in[4];
  const float* Wg1       = (const float*)d_in[5];
  const float* bg1       = (const float*)d_in[6];
  const float* Wg2       = (const float*)d_in[7];
  const float* bg2       = (const float*)d_in[8];
  const float* ln0_g     = (const float*)d_in[9];
  const float* ln0_b     = (const float*)d_in[10];
  const float* params_log= (const float*)d_in[11];
  const float* Win_re    = (const float*)d_in[12];
  const float* Win_im    = (const float*)d_in[13];
  const float* bin_re    = (const float*)d_in[14];
  const float* bin_im    = (const float*)d_in[15];
  const float* Wout_re   = (const float*)d_in[16];
  const float* Wout_im   = (const float*)d_in[17];
  const float* bout_re   = (const float*)d_in[18];
  const float* ln1_g     = (const float*)d_in[20];
  const float* ln1_b     = (const float*)d_in[21];
  const float* Wff1      = (const float*)d_in[22];
  const float* bff1      = (const float*)d_in[23];
  const float* Wff2      = (const float*)d_in[24];
  const float* bff2      = (const float*)d_in[25];
  const float* ln2_g     = (const float*)d_in[26];
  const float* ln2_b     = (const float*)d_in[27];
  float* out = (float*)d_out;

  dim3 blk(256);

  k_setup<<<6274, blk, 0, stream>>>(W_map, Wg1, Wg2, Win_re, Win_im,
                                    Wout_re, Wout_im, Wff1, Wff2,
                                    ids, params_log, bin_re, bin_im, item_emb);

  kg_llm <<<dim3(800,1), blk, 0, stream>>>(llm_emb, b_map, ids);
  kg_g1  <<<dim3(800,2), blk, 0, stream>>>(bg1);
  kg_gate<<<dim3(800,1), blk, 0, stream>>>(bg2, ln0_g, ln0_b);

  for (int l = 0; l < 2; l++){
    kg_h  <<<dim3(400,4), blk, 0, stream>>>(l);
    k_scan<<<dim3(16,CB), blk, 0, stream>>>(l);
    kg_out<<<dim3(800,1), blk, 0, stream>>>(l, bout_re + l*128, ln1_g + l*128, ln1_b + l*128);
    kg_ff1<<<dim3(400,4), blk, 0, stream>>>(l, bff1 + l*512);
    if (l == 0)
      kg_ff2 <<<dim3(800,1), blk, 0, stream>>>(l, bff2 + l*128, ln2_g + l*128, ln2_b + l*128);
    else
      kg_ff2o<<<dim3(800,1), blk, 0, stream>>>(l, bff2 + l*128, ln2_g + l*128, ln2_b + l*128, out);
  }
}

// Round 12
// 416.705 us; speedup vs baseline: 1.1122x; 1.0040x over previous
//
#include <hip/hip_runtime.h>
#include <hip/hip_bf16.h>

#define CB 256       // batch
#define CS 200       // seq
#define CH 128       // H
#define CH2 256      // 2H
#define CL 256       // padded scan length
#define CPAD 56
#define CBS (CB*CS)  // 51200 real tokens

typedef __attribute__((ext_vector_type(8))) short bf16x8;
typedef __attribute__((ext_vector_type(4))) float f32x4;

#define SB16 ((long)CBS*16)   // 16-channel chunk stride (token-major)

// ---------------- static device buffers ------------------------------------
// blocked bf16 activations: elem(c,tok) at (c>>4)*SB16 + tok*16 + (c&15)
__device__ __align__(16) __hip_bfloat16 g_cat [(size_t)CBS*256];
__device__ __align__(16) __hip_bfloat16 g_g1  [(size_t)CBS*256];
__device__ __align__(16) __hip_bfloat16 g_xb  [(size_t)CBS*128]; // residual
__device__ __align__(16) __hip_bfloat16 g_h   [(size_t)CBS*512]; // [re|im]
__device__ __align__(16) __hip_bfloat16 g_ffh [(size_t)CBS*512];
__device__ float g_mask[CB*CL];
__device__ float g_gamma2[2*512];
__device__ float g_bincat[2*512];
__device__ float2 g_lam[2*16*128*16];  // [l][ch16][j][dl] -> lambda^{j+1}
// bf16 weights, 16-K-chunk blocked: elem(r,c) at (c>>4)*(N*16) + r*16 + (c&15)
__device__ __align__(16) __hip_bfloat16 g_Wmap  [128*768];
__device__ __align__(16) __hip_bfloat16 g_Wg1   [256*256];
__device__ __align__(16) __hip_bfloat16 g_Wg2   [128*256];
__device__ __align__(16) __hip_bfloat16 g_Wincat[2*512*128];
__device__ __align__(16) __hip_bfloat16 g_Woutcat[2*128*512];
__device__ __align__(16) __hip_bfloat16 g_Wff1  [2*512*128];
__device__ __align__(16) __hip_bfloat16 g_Wff2  [2*128*512];

__device__ __forceinline__ short f2bf(float f){
  unsigned u = __float_as_uint(f);
  unsigned r = (u + 0x7fffu + ((u>>16)&1u)) >> 16;
  return (short)r;
}
__device__ __forceinline__ float bf2f(short s){
  return __uint_as_float(((unsigned)(unsigned short)s) << 16);
}

typedef const __attribute__((address_space(1))) void* gas1;
typedef __attribute__((address_space(3))) void* las3;
__device__ __forceinline__ void gl16(const void* g, void* l){
  __builtin_amdgcn_global_load_lds((gas1)g, (las3)l, 16, 0, 0);
}

// ---------------- merged setup: weights + mask + lambda prep + gather -------
__device__ __forceinline__ void wblk(__hip_bfloat16* dst, int N, int K, int i, float v){
  int r = i / K, c = i - r*K;
  ((short*)dst)[(long)(c>>4)*((long)N*16) + (long)r*16 + (c&15)] = f2bf(v);
}
__global__ void k_setup(const float* __restrict__ W_map, const float* __restrict__ Wg1,
                        const float* __restrict__ Wg2,
                        const float* __restrict__ Win_re, const float* __restrict__ Win_im,
                        const float* __restrict__ Wout_re, const float* __restrict__ Wout_im,
                        const float* __restrict__ Wff1, const float* __restrict__ Wff2,
                        const int* __restrict__ ids,
                        const float* __restrict__ pl,
                        const float* __restrict__ binre, const float* __restrict__ binim,
                        const float* __restrict__ item_emb){
  int bi = blockIdx.x, t = threadIdx.x;
  if (bi < 2816){
    int i = bi*256 + t;
    if (i < 98304){ wblk(g_Wmap, 128, 768, i, W_map[i]); return; }
    i -= 98304;
    if (i < 65536){ wblk(g_Wg1, 256, 256, i, Wg1[i]); return; }
    i -= 65536;
    if (i < 32768){ wblk(g_Wg2, 128, 256, i, Wg2[i]); return; }
    i -= 32768;
    int l = i / 262144; i -= l*262144;
    if (i < 32768){ wblk(g_Wincat + (long)l*65536, 512, 128, i,       Win_re[(long)l*32768 + i]); return; }
    i -= 32768;
    if (i < 32768){ wblk(g_Wincat + (long)l*65536, 512, 128, i+32768, Win_im[(long)l*32768 + i]); return; }
    i -= 32768;
    if (i < 65536){
      int r = i >> 9, c = i & 511;
      float v = (c < 256) ? Wout_re[(long)l*32768 + r*256 + c]
                          : -Wout_im[(long)l*32768 + r*256 + (c-256)];
      wblk(g_Woutcat + (long)l*65536, 128, 512, i, v); return;
    }
    i -= 65536;
    if (i < 65536){ wblk(g_Wff1 + (long)l*65536, 512, 128, i, Wff1[(long)l*65536 + i]); return; }
    i -= 65536;
    wblk(g_Wff2 + (long)l*65536, 128, 512, i, Wff2[(long)l*65536 + i]);
    return;
  }
  if (bi < 3072){
    int b = bi - 2816;
    float m = 0.f;
    if (t >= CPAD) m = (ids[b*CS + (t - CPAD)] > 0) ? 1.f : 0.f;
    g_mask[b*CL + t] = m;
    return;
  }
  if (bi < 3074){
    int l = bi - 3072, d = t;
    float nu = expf(pl[(l*3+0)*CH2 + d]);
    float th = expf(pl[(l*3+1)*CH2 + d]);
    float gm = expf(pl[(l*3+2)*CH2 + d]);
    g_gamma2[l*512 + d] = gm;       g_gamma2[l*512 + d + 256] = gm;
    g_bincat[l*512 + d] = binre[l*256 + d];
    g_bincat[l*512 + d + 256] = binim[l*256 + d];
    float r = expf(-nu);
    float lre = r*cosf(th), lim = r*sinf(th);
    float pr = lre, pi = lim;
    long base = ((long)l*16 + (d>>4))*2048 + (d&15);
    for (int k = 0; k < 128; k++){
      g_lam[base + (long)k*16] = make_float2(pr, pi);
      float nr = pr*lre - pi*lim;
      float ni = pr*lim + pi*lre;
      pr = nr; pi = ni;
    }
    return;
  }
  {
    // item-embedding gather, 16 tokens per block
    int tok = (bi - 3074)*16 + (t>>4);
    int cg = t & 15;
    int id = ids[tok];
    const float* p = item_emb + (size_t)id*128 + cg*8;
    float4 x0 = *(const float4*)p;
    float4 x1 = *(const float4*)(p + 4);
    bf16x8 v;
    v[0]=f2bf(x0.x); v[1]=f2bf(x0.y); v[2]=f2bf(x0.z); v[3]=f2bf(x0.w);
    v[4]=f2bf(x1.x); v[5]=f2bf(x1.y); v[6]=f2bf(x1.z); v[7]=f2bf(x1.w);
    *(bf16x8*)((short*)g_cat + (long)(cg>>1)*SB16 + (long)tok*16 + (cg&1)*8) = v;
  }
}

// ---------------- MFMA GEMM body, BK=64, gl16 staging, half-swizzled LDS ----
// Swizzle (rule #21, both-sides): LDS(r,h) holds global(r, h^((r>>2)&1));
// source address pre-permuted (h2), reads XOR sx. 16 lanes -> 8 banks (2-way, free).
// TM=128: EPI0, 2x2 waves (MF=4,NF=4).  TM=64: EPI0 2x2 (MF=2,NF=4);
// EPI1/2/3 4x1 waves (MF=1,NF=8): EPI1 LN(v+bias+xb)->xb;
// EPI2 sigmoid-mix-LN0->xb; EPI3 LN(v+bias+xb)->f32 out.
template<int TM, int ACT, int EPI, bool GATHER, bool COLSCALE>
__device__ __forceinline__ void mgemm_body(
    const short* __restrict__ A, const float* __restrict__ Af32, int ldaF,
    const short* __restrict__ W, long wBlk,
    const float* __restrict__ bias, const float* __restrict__ gamma,
    const int* __restrict__ gidx, short* __restrict__ C,
    long aBlk, int colOff, int K,
    const float* __restrict__ lnG, const float* __restrict__ lnB,
    float* __restrict__ outF)
{
  constexpr int ACH = TM*32;                 // bytes per 16-k A chunk
  __shared__ __align__(16) char lA[TM*128];
  __shared__ __align__(16) char lB[16384];
  constexpr int MF = (EPI==0) ? (TM/32) : 1;
  constexpr int NF = (EPI==0) ? 4 : 8;
  const int t = threadIdx.x;
  const int m0 = blockIdx.x*TM, n0 = blockIdx.y*128;
  const int lane = t & 63, wv = t >> 6;
  const int wr = (EPI==0)?(wv>>1):wv;
  const int wc = (EPI==0)?(wv&1):0;
  const int fr = lane & 15, fq = lane >> 4;
  const int rowB = (EPI==0) ? wr*(TM/2) : wv*16;
  const int colB = wc*64;
  const int lr2 = lane >> 1;
  const int h2 = (lane&1) ^ ((lane>>3)&1);         // pre-swizzled source half
  const int sx = ((fq&1) ^ ((fr>>2)&1)) << 4;      // swizzled read offset

  long gr0 = 0, gr1 = 0;
  if (GATHER){ gr0 = gidx[m0 + (t>>3)]; gr1 = gidx[m0 + (t>>3) + 32]; }

  f32x4 acc[MF][NF] = {};

  for (int k0 = 0; k0 < K; k0 += 64){
    if (TM == 128){
      #pragma unroll
      for (int cc = 0; cc < 4; cc++){
        const short* gp = A + (long)((k0>>4)+cc)*aBlk + (long)(m0 + wv*32 + lr2)*16 + h2*8;
        gl16(gp, lA + cc*4096 + wv*1024);
      }
      #pragma unroll
      for (int cc = 0; cc < 4; cc++){
        const short* gp = W + (long)((k0>>4)+cc)*wBlk + (long)(n0 + wv*32 + lr2)*16 + h2*8;
        gl16(gp, lB + cc*4096 + wv*1024);
      }
    } else {
      if (GATHER){
        #pragma unroll
        for (int rep = 0; rep < 2; rep++){
          int slot = t + rep*256;
          int row = slot>>3, cc = (slot>>1)&3, half = slot&1;
          int halfS = half ^ ((slot>>5)&1);          // swizzled LDS half
          long ar = rep ? gr1 : gr0;
          const float* p = Af32 + ar*(long)ldaF + k0 + cc*16 + half*8;
          float4 x0 = *(const float4*)p;
          float4 x1 = *(const float4*)(p + 4);
          bf16x8 v;
          v[0]=f2bf(x0.x); v[1]=f2bf(x0.y); v[2]=f2bf(x0.z); v[3]=f2bf(x0.w);
          v[4]=f2bf(x1.x); v[5]=f2bf(x1.y); v[6]=f2bf(x1.z); v[7]=f2bf(x1.w);
          *(bf16x8*)(lA + cc*2048 + row*32 + halfS*16) = v;
        }
      } else {
        #pragma unroll
        for (int p = 0; p < 2; p++){
          const short* gp = A + (long)((k0>>4)+wv)*aBlk + (long)(m0 + p*32 + lr2)*16 + h2*8;
          gl16(gp, lA + wv*2048 + p*1024);
        }
      }
      #pragma unroll
      for (int p = 0; p < 4; p++){
        const short* gp = W + (long)((k0>>4)+wv)*wBlk + (long)(n0 + p*32 + lr2)*16 + h2*8;
        gl16(gp, lB + wv*4096 + p*1024);
      }
    }
    __syncthreads();
    #pragma unroll
    for (int s = 0; s < 2; s++){
      const int cc = s*2 + (fq>>1);
      bf16x8 af[MF], bw[NF];
      #pragma unroll
      for (int m = 0; m < MF; m++)
        af[m] = *(const bf16x8*)(lA + cc*ACH + (rowB + m*16 + fr)*32 + sx);
      #pragma unroll
      for (int n = 0; n < NF; n++)
        bw[n] = *(const bf16x8*)(lB + cc*4096 + (colB + n*16 + fr)*32 + sx);
      #pragma unroll
      for (int m = 0; m < MF; m++)
        #pragma unroll
        for (int n = 0; n < NF; n++)
          acc[m][n] = __builtin_amdgcn_mfma_f32_16x16x32_bf16(af[m], bw[n], acc[m][n], 0, 0, 0);
    }
    __syncthreads();
  }

  if (EPI == 0){
    #pragma unroll
    for (int m = 0; m < MF; m++){
      #pragma unroll
      for (int j = 0; j < 4; j++){
        long row = m0 + rowB + m*16 + fq*4 + j;
        #pragma unroll
        for (int n = 0; n < NF; n++){
          int colL = n0 + colB + n*16 + fr;
          float v = acc[m][n][j] + bias[colL];
          if (COLSCALE) v *= gamma[colL];
          if (ACT == 1) v = 0.5f * v * (1.0f + erff(v * 0.70710678118654752f));
          int colS = colL + colOff;
          C[(long)(colS>>4)*SB16 + row*16 + (colS&15)] = f2bf(v);
        }
      }
    }
  } else {
    #pragma unroll
    for (int j = 0; j < 4; j++){
      int rt = rowB + fq*4 + j;
      long tok = m0 + rt;
      float vv[NF];
      float s1 = 0.f, s2 = 0.f;
      #pragma unroll
      for (int n = 0; n < NF; n++){
        int col = n*16 + fr;
        float v = acc[0][n][j] + bias[col];
        if (EPI == 2){
          v = 1.0f / (1.0f + expf(-v));
          float idv = bf2f(((const short*)g_cat)[(long)n*SB16 + tok*16 + fr]);
          float lmv = bf2f(((const short*)g_cat)[(long)(n+8)*SB16 + tok*16 + fr]);
          v = v*idv + (1.0f - v)*lmv;
        } else {
          v += bf2f(((const short*)g_xb)[(long)n*SB16 + tok*16 + fr]);
        }
        vv[n] = v; s1 += v; s2 += v*v;
      }
      #pragma unroll
      for (int off = 1; off < 16; off <<= 1){
        s1 += __shfl_xor(s1, off); s2 += __shfl_xor(s2, off);
      }
      float mu = s1 * (1.f/128.f);
      float var = s2 * (1.f/128.f) - mu*mu;
      float rstd = rsqrtf(var + 1e-12f);
      #pragma unroll
      for (int n = 0; n < NF; n++){
        int col = n*16 + fr;
        float o = (vv[n] - mu)*rstd*lnG[col] + lnB[col];
        if (EPI == 3)
          outF[tok*128 + col] = o;
        else
          ((short*)g_xb)[(long)n*SB16 + tok*16 + fr] = f2bf(o);
      }
    }
  }
}

// ---------------- named single-GEMM wrappers --------------------------------
__global__ __launch_bounds__(256) void kg_llm(const float* llm_emb, const float* b_map, const int* ids){
  mgemm_body<64,0,0,true,false>(nullptr, llm_emb, 768, (const short*)g_Wmap, 128L*16,
                                b_map, nullptr, ids, (short*)g_cat, 0, 128, 768, nullptr, nullptr, nullptr);
}
__global__ __launch_bounds__(256) void kg_g1(const float* bg1){
  mgemm_body<64,1,0,false,false>((const short*)g_cat, nullptr, 0, (const short*)g_Wg1, 256L*16,
                                 bg1, nullptr, nullptr, (short*)g_g1, SB16, 0, 256, nullptr, nullptr, nullptr);
}
__global__ __launch_bounds__(256) void kg_gate(const float* bg2, const float* ln0g, const float* ln0b){
  mgemm_body<64,0,2,false,false>((const short*)g_g1, nullptr, 0, (const short*)g_Wg2, 128L*16,
                                 bg2, nullptr, nullptr, nullptr, SB16, 0, 256, ln0g, ln0b, nullptr);
}
__global__ __launch_bounds__(256) void kg_h(int l){
  mgemm_body<128,0,0,false,true>((const short*)g_xb, nullptr, 0,
                                 (const short*)g_Wincat + (long)l*65536, 512L*16,
                                 g_bincat + l*512, g_gamma2 + l*512, nullptr, (short*)g_h,
                                 SB16, 0, 128, nullptr, nullptr, nullptr);
}
__global__ __launch_bounds__(256) void kg_out(int l, const float* bout, const float* g, const float* b){
  mgemm_body<64,0,1,false,false>((const short*)g_h, nullptr, 0,
                                 (const short*)g_Woutcat + (long)l*65536, 128L*16,
                                 bout, nullptr, nullptr, nullptr, SB16, 0, 512, g, b, nullptr);
}
__global__ __launch_bounds__(256) void kg_ff1(int l, const float* bff1){
  mgemm_body<128,1,0,false,false>((const short*)g_xb, nullptr, 0,
                                  (const short*)g_Wff1 + (long)l*65536, 512L*16,
                                  bff1, nullptr, nullptr, (short*)g_ffh, SB16, 0, 128, nullptr, nullptr, nullptr);
}
__global__ __launch_bounds__(256) void kg_ff2(int l, const float* bff2, const float* g, const float* b){
  mgemm_body<64,0,1,false,false>((const short*)g_ffh, nullptr, 0,
                                 (const short*)g_Wff2 + (long)l*65536, 128L*16,
                                 bff2, nullptr, nullptr, nullptr, SB16, 0, 512, g, b, nullptr);
}
__global__ __launch_bounds__(256) void kg_ff2o(int l, const float* bff2, const float* g, const float* b,
                                               float* outF){
  mgemm_body<64,0,3,false,false>((const short*)g_ffh, nullptr, 0,
                                 (const short*)g_Wff2 + (long)l*65536, 128L*16,
                                 bff2, nullptr, nullptr, nullptr, SB16, 0, 512, g, b, outF);
}

// ---------------- blocked LRU scan (r6 LDS version, proven) -----------------
__global__ __launch_bounds__(256) void k_scan(int l){
  __shared__ __align__(16) float sre[CL*16];
  __shared__ __align__(16) float sim[CL*16];
  __shared__ float smask[CL];
  int b = blockIdx.y, ch = blockIdx.x;  // ch 0..15
  int tid = threadIdx.x;
  short* Hre = (short*)g_h + (long)ch*SB16 + (long)b*CS*16;
  short* Him = (short*)g_h + (long)(ch+16)*SB16 + (long)b*CS*16;
  smask[tid] = g_mask[b*CL + tid];
  for (int q = tid; q < 224; q += 256){    // zero pad rows 0..55
    ((float4*)sre)[q] = make_float4(0.f,0.f,0.f,0.f);
    ((float4*)sim)[q] = make_float4(0.f,0.f,0.f,0.f);
  }
  for (int q = tid; q < 400; q += 256){    // 200 tokens * 16 / 8
    bf16x8 r8 = ((const bf16x8*)Hre)[q];
    bf16x8 i8 = ((const bf16x8*)Him)[q];
    int base = 896 + q*8;
    #pragma unroll
    for (int k = 0; k < 8; k++){ sre[base+k] = bf2f(r8[k]); sim[base+k] = bf2f(i8[k]); }
  }
  __syncthreads();
  const float2* lam = g_lam + ((long)l*16 + ch)*2048;
  const int dl = tid & 15, u0 = tid >> 4;
  for (int i = 1; i <= 8; i++){
    int hl = 1 << (i-1);
    #pragma unroll
    for (int k = 0; k < 8; k++){
      int u = u0 + k*16;
      int blkI = u >> (i-1), j = u & (hl-1);
      int p = (blkI << i) + hl - 1;
      int tt = p + 1 + j;
      float mv = smask[p];
      float2 L = lam[j*16 + dl];
      float hr = sre[p*16+dl], hi = sim[p*16+dl];
      sre[tt*16+dl] += (L.x*hr - L.y*hi) * mv;
      sim[tt*16+dl] += (L.x*hi + L.y*hr) * mv;
    }
    __syncthreads();
  }
  for (int q = tid; q < 400; q += 256){
    int base = 896 + q*8;
    bf16x8 r8, i8;
    #pragma unroll
    for (int k = 0; k < 8; k++){ r8[k] = f2bf(sre[base+k]); i8[k] = f2bf(sim[base+k]); }
    ((bf16x8*)Hre)[q] = r8;
    ((bf16x8*)Him)[q] = i8;
  }
}

// ---------------------------------------------------------------------------
extern "C" void kernel_launch(void* const* d_in, const int* in_sizes, int n_in,
                              void* d_out, int out_size, void* d_ws, size_t ws_size,
                              hipStream_t stream) {
  const int*   ids       = (const int*)  d_in[0];
  const float* item_emb  = (const float*)d_in[1];
  const float* llm_emb   = (const float*)d_in[2];
  const float* W_map     = (const float*)d_in[3];
  const float* b_map     = (const float*)d_in[4];
  const float* Wg1       = (const float*)d_in[5];
  const float* bg1       = (const float*)d_in[6];
  const float* Wg2       = (const float*)d_in[7];
  const float* bg2       = (const float*)d_in[8];
  const float* ln0_g     = (const float*)d_in[9];
  const float* ln0_b     = (const float*)d_in[10];
  const float* params_log= (const float*)d_in[11];
  const float* Win_re    = (const float*)d_in[12];
  const float* Win_im    = (const float*)d_in[13];
  const float* bin_re    = (const float*)d_in[14];
  const float* bin_im    = (const float*)d_in[15];
  const float* Wout_re   = (const float*)d_in[16];
  const float* Wout_im   = (const float*)d_in[17];
  const float* bout_re   = (const float*)d_in[18];
  const float* ln1_g     = (const float*)d_in[20];
  const float* ln1_b     = (const float*)d_in[21];
  const float* Wff1      = (const float*)d_in[22];
  const float* bff1      = (const float*)d_in[23];
  const float* Wff2      = (const float*)d_in[24];
  const float* bff2      = (const float*)d_in[25];
  const float* ln2_g     = (const float*)d_in[26];
  const float* ln2_b     = (const float*)d_in[27];
  float* out = (float*)d_out;

  dim3 blk(256);

  k_setup<<<6274, blk, 0, stream>>>(W_map, Wg1, Wg2, Win_re, Win_im,
                                    Wout_re, Wout_im, Wff1, Wff2,
                                    ids, params_log, bin_re, bin_im, item_emb);

  kg_llm <<<dim3(800,1), blk, 0, stream>>>(llm_emb, b_map, ids);
  kg_g1  <<<dim3(800,2), blk, 0, stream>>>(bg1);
  kg_gate<<<dim3(800,1), blk, 0, stream>>>(bg2, ln0_g, ln0_b);

  for (int l = 0; l < 2; l++){
    kg_h  <<<dim3(400,4), blk, 0, stream>>>(l);
    k_scan<<<dim3(16,CB), blk, 0, stream>>>(l);
    kg_out<<<dim3(800,1), blk, 0, stream>>>(l, bout_re + l*128, ln1_g + l*128, ln1_b + l*128);
    kg_ff1<<<dim3(400,4), blk, 0, stream>>>(l, bff1 + l*512);
    if (l == 0)
      kg_ff2 <<<dim3(800,1), blk, 0, stream>>>(l, bff2 + l*128, ln2_g + l*128, ln2_b + l*128);
    else
      kg_ff2o<<<dim3(800,1), blk, 0, stream>>>(l, bff2 + l*128, ln2_g + l*128, ln2_b + l*128, out);
  }
}

// Round 14
// 414.629 us; speedup vs baseline: 1.1178x; 1.0050x over previous
//
#include <hip/hip_runtime.h>
#include <hip/hip_bf16.h>

#define CB 256       // batch
#define CS 200       // seq
#define CH 128       // H
#define CH2 256      // 2H
#define CL 256       // padded scan length
#define CPAD 56
#define CBS (CB*CS)  // 51200 real tokens

typedef __attribute__((ext_vector_type(8))) short bf16x8;
typedef __attribute__((ext_vector_type(4))) float f32x4;

#define SB16 ((long)CBS*16)   // 16-channel chunk stride (token-major)

// ---------------- static device buffers ------------------------------------
// blocked bf16 activations: elem(c,tok) at (c>>4)*SB16 + tok*16 + (c&15)
__device__ __align__(16) __hip_bfloat16 g_cat [(size_t)CBS*256];
__device__ __align__(16) __hip_bfloat16 g_g1  [(size_t)CBS*256];
__device__ __align__(16) __hip_bfloat16 g_xb  [(size_t)CBS*128]; // residual
__device__ __align__(16) __hip_bfloat16 g_h   [(size_t)CBS*512]; // [re|im]
__device__ __align__(16) __hip_bfloat16 g_ffh [(size_t)CBS*512];
__device__ float g_mask[CB*CL];
__device__ float g_gamma2[2*512];
__device__ float g_bincat[2*512];
__device__ float2 g_lam[2*16*128*16];  // [l][ch16][j][dl] -> lambda^{j+1}
// bf16 weights, 16-K-chunk blocked: elem(r,c) at (c>>4)*(N*16) + r*16 + (c&15)
__device__ __align__(16) __hip_bfloat16 g_Wmap  [128*768];
__device__ __align__(16) __hip_bfloat16 g_Wg1   [256*256];
__device__ __align__(16) __hip_bfloat16 g_Wg2   [128*256];
__device__ __align__(16) __hip_bfloat16 g_Wincat[2*512*128];
__device__ __align__(16) __hip_bfloat16 g_Woutcat[2*128*512];
__device__ __align__(16) __hip_bfloat16 g_Wff1  [2*512*128];
__device__ __align__(16) __hip_bfloat16 g_Wff2  [2*128*512];

__device__ __forceinline__ short f2bf(float f){
  unsigned u = __float_as_uint(f);
  unsigned r = (u + 0x7fffu + ((u>>16)&1u)) >> 16;
  return (short)r;
}
__device__ __forceinline__ float bf2f(short s){
  return __uint_as_float(((unsigned)(unsigned short)s) << 16);
}

typedef const __attribute__((address_space(1))) void* gas1;
typedef __attribute__((address_space(3))) void* las3;
__device__ __forceinline__ void gl16(const void* g, void* l){
  __builtin_amdgcn_global_load_lds((gas1)g, (las3)l, 16, 0, 0);
}

// ---------------- merged setup: weights + mask + lambda prep + gather -------
__device__ __forceinline__ void wblk(__hip_bfloat16* dst, int N, int K, int i, float v){
  int r = i / K, c = i - r*K;
  ((short*)dst)[(long)(c>>4)*((long)N*16) + (long)r*16 + (c&15)] = f2bf(v);
}
__global__ void k_setup(const float* __restrict__ W_map, const float* __restrict__ Wg1,
                        const float* __restrict__ Wg2,
                        const float* __restrict__ Win_re, const float* __restrict__ Win_im,
                        const float* __restrict__ Wout_re, const float* __restrict__ Wout_im,
                        const float* __restrict__ Wff1, const float* __restrict__ Wff2,
                        const int* __restrict__ ids,
                        const float* __restrict__ pl,
                        const float* __restrict__ binre, const float* __restrict__ binim,
                        const float* __restrict__ item_emb){
  int bi = blockIdx.x, t = threadIdx.x;
  if (bi < 2816){
    int i = bi*256 + t;
    if (i < 98304){ wblk(g_Wmap, 128, 768, i, W_map[i]); return; }
    i -= 98304;
    if (i < 65536){ wblk(g_Wg1, 256, 256, i, Wg1[i]); return; }
    i -= 65536;
    if (i < 32768){ wblk(g_Wg2, 128, 256, i, Wg2[i]); return; }
    i -= 32768;
    int l = i / 262144; i -= l*262144;
    if (i < 32768){ wblk(g_Wincat + (long)l*65536, 512, 128, i,       Win_re[(long)l*32768 + i]); return; }
    i -= 32768;
    if (i < 32768){ wblk(g_Wincat + (long)l*65536, 512, 128, i+32768, Win_im[(long)l*32768 + i]); return; }
    i -= 32768;
    if (i < 65536){
      int r = i >> 9, c = i & 511;
      float v = (c < 256) ? Wout_re[(long)l*32768 + r*256 + c]
                          : -Wout_im[(long)l*32768 + r*256 + (c-256)];
      wblk(g_Woutcat + (long)l*65536, 128, 512, i, v); return;
    }
    i -= 65536;
    if (i < 65536){ wblk(g_Wff1 + (long)l*65536, 512, 128, i, Wff1[(long)l*65536 + i]); return; }
    i -= 65536;
    wblk(g_Wff2 + (long)l*65536, 128, 512, i, Wff2[(long)l*65536 + i]);
    return;
  }
  if (bi < 3072){
    int b = bi - 2816;
    float m = 0.f;
    if (t >= CPAD) m = (ids[b*CS + (t - CPAD)] > 0) ? 1.f : 0.f;
    g_mask[b*CL + t] = m;
    return;
  }
  if (bi < 3074){
    int l = bi - 3072, d = t;
    float nu = expf(pl[(l*3+0)*CH2 + d]);
    float th = expf(pl[(l*3+1)*CH2 + d]);
    float gm = expf(pl[(l*3+2)*CH2 + d]);
    g_gamma2[l*512 + d] = gm;       g_gamma2[l*512 + d + 256] = gm;
    g_bincat[l*512 + d] = binre[l*256 + d];
    g_bincat[l*512 + d + 256] = binim[l*256 + d];
    float r = expf(-nu);
    float lre = r*cosf(th), lim = r*sinf(th);
    float pr = lre, pi = lim;
    long base = ((long)l*16 + (d>>4))*2048 + (d&15);
    for (int k = 0; k < 128; k++){
      g_lam[base + (long)k*16] = make_float2(pr, pi);
      float nr = pr*lre - pi*lim;
      float ni = pr*lim + pi*lre;
      pr = nr; pi = ni;
    }
    return;
  }
  {
    // item-embedding gather, 16 tokens per block
    int tok = (bi - 3074)*16 + (t>>4);
    int cg = t & 15;
    int id = ids[tok];
    const float* p = item_emb + (size_t)id*128 + cg*8;
    float4 x0 = *(const float4*)p;
    float4 x1 = *(const float4*)(p + 4);
    bf16x8 v;
    v[0]=f2bf(x0.x); v[1]=f2bf(x0.y); v[2]=f2bf(x0.z); v[3]=f2bf(x0.w);
    v[4]=f2bf(x1.x); v[5]=f2bf(x1.y); v[6]=f2bf(x1.z); v[7]=f2bf(x1.w);
    *(bf16x8*)((short*)g_cat + (long)(cg>>1)*SB16 + (long)tok*16 + (cg&1)*8) = v;
  }
}

// ---------------- MFMA GEMM body, BK=64, gl16 staging, half-swizzled LDS ----
// (r12-proven, unchanged)
template<int TM, int ACT, int EPI, bool GATHER, bool COLSCALE>
__device__ __forceinline__ void mgemm_body(
    const short* __restrict__ A, const float* __restrict__ Af32, int ldaF,
    const short* __restrict__ W, long wBlk,
    const float* __restrict__ bias, const float* __restrict__ gamma,
    const int* __restrict__ gidx, short* __restrict__ C,
    long aBlk, int colOff, int K,
    const float* __restrict__ lnG, const float* __restrict__ lnB,
    float* __restrict__ outF)
{
  constexpr int ACH = TM*32;                 // bytes per 16-k A chunk
  __shared__ __align__(16) char lA[TM*128];
  __shared__ __align__(16) char lB[16384];
  constexpr int MF = (EPI==0) ? (TM/32) : 1;
  constexpr int NF = (EPI==0) ? 4 : 8;
  const int t = threadIdx.x;
  const int m0 = blockIdx.x*TM, n0 = blockIdx.y*128;
  const int lane = t & 63, wv = t >> 6;
  const int wr = (EPI==0)?(wv>>1):wv;
  const int wc = (EPI==0)?(wv&1):0;
  const int fr = lane & 15, fq = lane >> 4;
  const int rowB = (EPI==0) ? wr*(TM/2) : wv*16;
  const int colB = wc*64;
  const int lr2 = lane >> 1;
  const int h2 = (lane&1) ^ ((lane>>3)&1);         // pre-swizzled source half
  const int sx = ((fq&1) ^ ((fr>>2)&1)) << 4;      // swizzled read offset

  long gr0 = 0, gr1 = 0;
  if (GATHER){ gr0 = gidx[m0 + (t>>3)]; gr1 = gidx[m0 + (t>>3) + 32]; }

  f32x4 acc[MF][NF] = {};

  for (int k0 = 0; k0 < K; k0 += 64){
    if (TM == 128){
      #pragma unroll
      for (int cc = 0; cc < 4; cc++){
        const short* gp = A + (long)((k0>>4)+cc)*aBlk + (long)(m0 + wv*32 + lr2)*16 + h2*8;
        gl16(gp, lA + cc*4096 + wv*1024);
      }
      #pragma unroll
      for (int cc = 0; cc < 4; cc++){
        const short* gp = W + (long)((k0>>4)+cc)*wBlk + (long)(n0 + wv*32 + lr2)*16 + h2*8;
        gl16(gp, lB + cc*4096 + wv*1024);
      }
    } else {
      if (GATHER){
        #pragma unroll
        for (int rep = 0; rep < 2; rep++){
          int slot = t + rep*256;
          int row = slot>>3, cc = (slot>>1)&3, half = slot&1;
          int halfS = half ^ ((slot>>5)&1);          // swizzled LDS half
          long ar = rep ? gr1 : gr0;
          const float* p = Af32 + ar*(long)ldaF + k0 + cc*16 + half*8;
          float4 x0 = *(const float4*)p;
          float4 x1 = *(const float4*)(p + 4);
          bf16x8 v;
          v[0]=f2bf(x0.x); v[1]=f2bf(x0.y); v[2]=f2bf(x0.z); v[3]=f2bf(x0.w);
          v[4]=f2bf(x1.x); v[5]=f2bf(x1.y); v[6]=f2bf(x1.z); v[7]=f2bf(x1.w);
          *(bf16x8*)(lA + cc*2048 + row*32 + halfS*16) = v;
        }
      } else {
        #pragma unroll
        for (int p = 0; p < 2; p++){
          const short* gp = A + (long)((k0>>4)+wv)*aBlk + (long)(m0 + p*32 + lr2)*16 + h2*8;
          gl16(gp, lA + wv*2048 + p*1024);
        }
      }
      #pragma unroll
      for (int p = 0; p < 4; p++){
        const short* gp = W + (long)((k0>>4)+wv)*wBlk + (long)(n0 + p*32 + lr2)*16 + h2*8;
        gl16(gp, lB + wv*4096 + p*1024);
      }
    }
    __syncthreads();
    #pragma unroll
    for (int s = 0; s < 2; s++){
      const int cc = s*2 + (fq>>1);
      bf16x8 af[MF], bw[NF];
      #pragma unroll
      for (int m = 0; m < MF; m++)
        af[m] = *(const bf16x8*)(lA + cc*ACH + (rowB + m*16 + fr)*32 + sx);
      #pragma unroll
      for (int n = 0; n < NF; n++)
        bw[n] = *(const bf16x8*)(lB + cc*4096 + (colB + n*16 + fr)*32 + sx);
      #pragma unroll
      for (int m = 0; m < MF; m++)
        #pragma unroll
        for (int n = 0; n < NF; n++)
          acc[m][n] = __builtin_amdgcn_mfma_f32_16x16x32_bf16(af[m], bw[n], acc[m][n], 0, 0, 0);
    }
    __syncthreads();
  }

  if (EPI == 0){
    #pragma unroll
    for (int m = 0; m < MF; m++){
      #pragma unroll
      for (int j = 0; j < 4; j++){
        long row = m0 + rowB + m*16 + fq*4 + j;
        #pragma unroll
        for (int n = 0; n < NF; n++){
          int colL = n0 + colB + n*16 + fr;
          float v = acc[m][n][j] + bias[colL];
          if (COLSCALE) v *= gamma[colL];
          if (ACT == 1) v = 0.5f * v * (1.0f + erff(v * 0.70710678118654752f));
          int colS = colL + colOff;
          C[(long)(colS>>4)*SB16 + row*16 + (colS&15)] = f2bf(v);
        }
      }
    }
  } else {
    #pragma unroll
    for (int j = 0; j < 4; j++){
      int rt = rowB + fq*4 + j;
      long tok = m0 + rt;
      float vv[NF];
      float s1 = 0.f, s2 = 0.f;
      #pragma unroll
      for (int n = 0; n < NF; n++){
        int col = n*16 + fr;
        float v = acc[0][n][j] + bias[col];
        if (EPI == 2){
          v = 1.0f / (1.0f + expf(-v));
          float idv = bf2f(((const short*)g_cat)[(long)n*SB16 + tok*16 + fr]);
          float lmv = bf2f(((const short*)g_cat)[(long)(n+8)*SB16 + tok*16 + fr]);
          v = v*idv + (1.0f - v)*lmv;
        } else {
          v += bf2f(((const short*)g_xb)[(long)n*SB16 + tok*16 + fr]);
        }
        vv[n] = v; s1 += v; s2 += v*v;
      }
      #pragma unroll
      for (int off = 1; off < 16; off <<= 1){
        s1 += __shfl_xor(s1, off); s2 += __shfl_xor(s2, off);
      }
      float mu = s1 * (1.f/128.f);
      float var = s2 * (1.f/128.f) - mu*mu;
      float rstd = rsqrtf(var + 1e-12f);
      #pragma unroll
      for (int n = 0; n < NF; n++){
        int col = n*16 + fr;
        float o = (vv[n] - mu)*rstd*lnG[col] + lnB[col];
        if (EPI == 3)
          outF[tok*128 + col] = o;
        else
          ((short*)g_xb)[(long)n*SB16 + tok*16 + fr] = f2bf(o);
      }
    }
  }
}

// ---------------- named single-GEMM wrappers --------------------------------
__global__ __launch_bounds__(256) void kg_llm(const float* llm_emb, const float* b_map, const int* ids){
  mgemm_body<64,0,0,true,false>(nullptr, llm_emb, 768, (const short*)g_Wmap, 128L*16,
                                b_map, nullptr, ids, (short*)g_cat, 0, 128, 768, nullptr, nullptr, nullptr);
}
__global__ __launch_bounds__(256) void kg_g1(const float* bg1){
  mgemm_body<64,1,0,false,false>((const short*)g_cat, nullptr, 0, (const short*)g_Wg1, 256L*16,
                                 bg1, nullptr, nullptr, (short*)g_g1, SB16, 0, 256, nullptr, nullptr, nullptr);
}
__global__ __launch_bounds__(256) void kg_gate(const float* bg2, const float* ln0g, const float* ln0b){
  mgemm_body<64,0,2,false,false>((const short*)g_g1, nullptr, 0, (const short*)g_Wg2, 128L*16,
                                 bg2, nullptr, nullptr, nullptr, SB16, 0, 256, ln0g, ln0b, nullptr);
}
__global__ __launch_bounds__(256) void kg_h(int l){
  mgemm_body<128,0,0,false,true>((const short*)g_xb, nullptr, 0,
                                 (const short*)g_Wincat + (long)l*65536, 512L*16,
                                 g_bincat + l*512, g_gamma2 + l*512, nullptr, (short*)g_h,
                                 SB16, 0, 128, nullptr, nullptr, nullptr);
}
__global__ __launch_bounds__(256) void kg_out(int l, const float* bout, const float* g, const float* b){
  mgemm_body<64,0,1,false,false>((const short*)g_h, nullptr, 0,
                                 (const short*)g_Woutcat + (long)l*65536, 128L*16,
                                 bout, nullptr, nullptr, nullptr, SB16, 0, 512, g, b, nullptr);
}
__global__ __launch_bounds__(256) void kg_ff1(int l, const float* bff1){
  mgemm_body<128,1,0,false,false>((const short*)g_xb, nullptr, 0,
                                  (const short*)g_Wff1 + (long)l*65536, 512L*16,
                                  bff1, nullptr, nullptr, (short*)g_ffh, SB16, 0, 128, nullptr, nullptr, nullptr);
}
__global__ __launch_bounds__(256) void kg_ff2(int l, const float* bff2, const float* g, const float* b){
  mgemm_body<64,0,1,false,false>((const short*)g_ffh, nullptr, 0,
                                 (const short*)g_Wff2 + (long)l*65536, 128L*16,
                                 bff2, nullptr, nullptr, nullptr, SB16, 0, 512, g, b, nullptr);
}
__global__ __launch_bounds__(256) void kg_ff2o(int l, const float* bff2, const float* g, const float* b,
                                               float* outF){
  mgemm_body<64,0,3,false,false>((const short*)g_ffh, nullptr, 0,
                                 (const short*)g_Wff2 + (long)l*65536, 128L*16,
                                 bff2, nullptr, nullptr, nullptr, SB16, 0, 512, g, b, outF);
}

// ---------------- blocked LRU scan (r6 LDS version, proven) -----------------
__global__ __launch_bounds__(256) void k_scan(int l){
  __shared__ __align__(16) float sre[CL*16];
  __shared__ __align__(16) float sim[CL*16];
  __shared__ float smask[CL];
  int b = blockIdx.y, ch = blockIdx.x;  // ch 0..15
  int tid = threadIdx.x;
  short* Hre = (short*)g_h + (long)ch*SB16 + (long)b*CS*16;
  short* Him = (short*)g_h + (long)(ch+16)*SB16 + (long)b*CS*16;
  smask[tid] = g_mask[b*CL + tid];
  for (int q = tid; q < 224; q += 256){    // zero pad rows 0..55
    ((float4*)sre)[q] = make_float4(0.f,0.f,0.f,0.f);
    ((float4*)sim)[q] = make_float4(0.f,0.f,0.f,0.f);
  }
  for (int q = tid; q < 400; q += 256){    // 200 tokens * 16 / 8
    bf16x8 r8 = ((const bf16x8*)Hre)[q];
    bf16x8 i8 = ((const bf16x8*)Him)[q];
    int base = 896 + q*8;
    #pragma unroll
    for (int k = 0; k < 8; k++){ sre[base+k] = bf2f(r8[k]); sim[base+k] = bf2f(i8[k]); }
  }
  __syncthreads();
  const float2* lam = g_lam + ((long)l*16 + ch)*2048;
  const int dl = tid & 15, u0 = tid >> 4;
  for (int i = 1; i <= 8; i++){
    int hl = 1 << (i-1);
    #pragma unroll
    for (int k = 0; k < 8; k++){
      int u = u0 + k*16;
      int blkI = u >> (i-1), j = u & (hl-1);
      int p = (blkI << i) + hl - 1;
      int tt = p + 1 + j;
      float mv = smask[p];
      float2 L = lam[j*16 + dl];
      float hr = sre[p*16+dl], hi = sim[p*16+dl];
      sre[tt*16+dl] += (L.x*hr - L.y*hi) * mv;
      sim[tt*16+dl] += (L.x*hi + L.y*hr) * mv;
    }
    __syncthreads();
  }
  for (int q = tid; q < 400; q += 256){
    int base = 896 + q*8;
    bf16x8 r8, i8;
    #pragma unroll
    for (int k = 0; k < 8; k++){ r8[k] = f2bf(sre[base+k]); i8[k] = f2bf(sim[base+k]); }
    ((bf16x8*)Hre)[q] = r8;
    ((bf16x8*)Him)[q] = i8;
  }
}

// ---------------------------------------------------------------------------
extern "C" void kernel_launch(void* const* d_in, const int* in_sizes, int n_in,
                              void* d_out, int out_size, void* d_ws, size_t ws_size,
                              hipStream_t stream) {
  const int*   ids       = (const int*)  d_in[0];
  const float* item_emb  = (const float*)d_in[1];
  const float* llm_emb   = (const float*)d_in[2];
  const float* W_map     = (const float*)d_in[3];
  const float* b_map     = (const float*)d_in[4];
  const float* Wg1       = (const float*)d_in[5];
  const float* bg1       = (const float*)d_in[6];
  const float* Wg2       = (const float*)d_in[7];
  const float* bg2       = (const float*)d_in[8];
  const float* ln0_g     = (const float*)d_in[9];
  const float* ln0_b     = (const float*)d_in[10];
  const float* params_log= (const float*)d_in[11];
  const float* Win_re    = (const float*)d_in[12];
  const float* Win_im    = (const float*)d_in[13];
  const float* bin_re    = (const float*)d_in[14];
  const float* bin_im    = (const float*)d_in[15];
  const float* Wout_re   = (const float*)d_in[16];
  const float* Wout_im   = (const float*)d_in[17];
  const float* bout_re   = (const float*)d_in[18];
  const float* ln1_g     = (const float*)d_in[20];
  const float* ln1_b     = (const float*)d_in[21];
  const float* Wff1      = (const float*)d_in[22];
  const float* bff1      = (const float*)d_in[23];
  const float* Wff2      = (const float*)d_in[24];
  const float* bff2      = (const float*)d_in[25];
  const float* ln2_g     = (const float*)d_in[26];
  const float* ln2_b     = (const float*)d_in[27];
  float* out = (float*)d_out;

  dim3 blk(256);

  k_setup<<<6274, blk, 0, stream>>>(W_map, Wg1, Wg2, Win_re, Win_im,
                                    Wout_re, Wout_im, Wff1, Wff2,
                                    ids, params_log, bin_re, bin_im, item_emb);

  kg_llm <<<dim3(800,1), blk, 0, stream>>>(llm_emb, b_map, ids);
  kg_g1  <<<dim3(800,2), blk, 0, stream>>>(bg1);
  kg_gate<<<dim3(800,1), blk, 0, stream>>>(bg2, ln0_g, ln0_b);

  for (int l = 0; l < 2; l++){
    kg_h  <<<dim3(400,4), blk, 0, stream>>>(l);
    k_scan<<<dim3(16,CB), blk, 0, stream>>>(l);
    kg_out<<<dim3(800,1), blk, 0, stream>>>(l, bout_re + l*128, ln1_g + l*128, ln1_b + l*128);
    kg_ff1<<<dim3(400,4), blk, 0, stream>>>(l, bff1 + l*512);
    if (l == 0)
      kg_ff2 <<<dim3(800,1), blk, 0, stream>>>(l, bff2 + l*128, ln2_g + l*128, ln2_b + l*128);
    else
      kg_ff2o<<<dim3(800,1), blk, 0, stream>>>(l, bff2 + l*128, ln2_g + l*128, ln2_b + l*128, out);
  }
}

// Round 15
// 403.258 us; speedup vs baseline: 1.1493x; 1.0282x over previous
//
#include <hip/hip_runtime.h>
#include <hip/hip_bf16.h>

#define CB 256       // batch
#define CS 200       // seq
#define CH 128       // H
#define CH2 256      // 2H
#define CL 256       // padded scan length
#define CPAD 56
#define CBS (CB*CS)  // 51200 real tokens

typedef __attribute__((ext_vector_type(8))) short bf16x8;
typedef __attribute__((ext_vector_type(4))) float f32x4;

#define SB16 ((long)CBS*16)   // 16-channel chunk stride (token-major)

// ---------------- static device buffers ------------------------------------
// blocked bf16 activations: elem(c,tok) at (c>>4)*SB16 + tok*16 + (c&15)
__device__ __align__(16) __hip_bfloat16 g_cat [(size_t)CBS*256];
__device__ __align__(16) __hip_bfloat16 g_g1  [(size_t)CBS*256];
__device__ __align__(16) __hip_bfloat16 g_xb  [(size_t)CBS*128]; // residual
__device__ __align__(16) __hip_bfloat16 g_h   [(size_t)CBS*512]; // [re|im]
__device__ __align__(16) __hip_bfloat16 g_ffh [(size_t)CBS*512];
__device__ float g_mask[CB*CL];
__device__ float g_gamma2[2*512];
__device__ float g_bincat[2*512];
__device__ float2 g_lam[2*16*128*16];  // [l][ch16][j][dl] -> lambda^{j+1}
// bf16 weights, 16-K-chunk blocked: elem(r,c) at (c>>4)*(N*16) + r*16 + (c&15)
__device__ __align__(16) __hip_bfloat16 g_Wmap  [128*768];
__device__ __align__(16) __hip_bfloat16 g_Wg1   [256*256];
__device__ __align__(16) __hip_bfloat16 g_Wg2   [128*256];
__device__ __align__(16) __hip_bfloat16 g_Wincat[2*512*128];
__device__ __align__(16) __hip_bfloat16 g_Woutcat[2*128*512];
__device__ __align__(16) __hip_bfloat16 g_Wff1  [2*512*128];
__device__ __align__(16) __hip_bfloat16 g_Wff2  [2*128*512];

__device__ __forceinline__ short f2bf(float f){
  unsigned u = __float_as_uint(f);
  unsigned r = (u + 0x7fffu + ((u>>16)&1u)) >> 16;
  return (short)r;
}
__device__ __forceinline__ float bf2f(short s){
  return __uint_as_float(((unsigned)(unsigned short)s) << 16);
}

typedef const __attribute__((address_space(1))) void* gas1;
typedef __attribute__((address_space(3))) void* las3;
__device__ __forceinline__ void gl16(const void* g, void* l){
  __builtin_amdgcn_global_load_lds((gas1)g, (las3)l, 16, 0, 0);
}

// ---------------- merged setup: weights + mask + lambda prep + gather -------
__device__ __forceinline__ void wblk(__hip_bfloat16* dst, int N, int K, int i, float v){
  int r = i / K, c = i - r*K;
  ((short*)dst)[(long)(c>>4)*((long)N*16) + (long)r*16 + (c&15)] = f2bf(v);
}
__global__ void k_setup(const float* __restrict__ W_map, const float* __restrict__ Wg1,
                        const float* __restrict__ Wg2,
                        const float* __restrict__ Win_re, const float* __restrict__ Win_im,
                        const float* __restrict__ Wout_re, const float* __restrict__ Wout_im,
                        const float* __restrict__ Wff1, const float* __restrict__ Wff2,
                        const int* __restrict__ ids,
                        const float* __restrict__ pl,
                        const float* __restrict__ binre, const float* __restrict__ binim,
                        const float* __restrict__ item_emb){
  int bi = blockIdx.x, t = threadIdx.x;
  if (bi < 2816){
    int i = bi*256 + t;
    if (i < 98304){ wblk(g_Wmap, 128, 768, i, W_map[i]); return; }
    i -= 98304;
    if (i < 65536){ wblk(g_Wg1, 256, 256, i, Wg1[i]); return; }
    i -= 65536;
    if (i < 32768){ wblk(g_Wg2, 128, 256, i, Wg2[i]); return; }
    i -= 32768;
    int l = i / 262144; i -= l*262144;
    if (i < 32768){ wblk(g_Wincat + (long)l*65536, 512, 128, i,       Win_re[(long)l*32768 + i]); return; }
    i -= 32768;
    if (i < 32768){ wblk(g_Wincat + (long)l*65536, 512, 128, i+32768, Win_im[(long)l*32768 + i]); return; }
    i -= 32768;
    if (i < 65536){
      int r = i >> 9, c = i & 511;
      float v = (c < 256) ? Wout_re[(long)l*32768 + r*256 + c]
                          : -Wout_im[(long)l*32768 + r*256 + (c-256)];
      wblk(g_Woutcat + (long)l*65536, 128, 512, i, v); return;
    }
    i -= 65536;
    if (i < 65536){ wblk(g_Wff1 + (long)l*65536, 512, 128, i, Wff1[(long)l*65536 + i]); return; }
    i -= 65536;
    wblk(g_Wff2 + (long)l*65536, 128, 512, i, Wff2[(long)l*65536 + i]);
    return;
  }
  if (bi < 3072){
    int b = bi - 2816;
    float m = 0.f;
    if (t >= CPAD) m = (ids[b*CS + (t - CPAD)] > 0) ? 1.f : 0.f;
    g_mask[b*CL + t] = m;
    return;
  }
  if (bi < 3074){
    int l = bi - 3072, d = t;
    float nu = expf(pl[(l*3+0)*CH2 + d]);
    float th = expf(pl[(l*3+1)*CH2 + d]);
    float gm = expf(pl[(l*3+2)*CH2 + d]);
    g_gamma2[l*512 + d] = gm;       g_gamma2[l*512 + d + 256] = gm;
    g_bincat[l*512 + d] = binre[l*256 + d];
    g_bincat[l*512 + d + 256] = binim[l*256 + d];
    float r = expf(-nu);
    float lre = r*cosf(th), lim = r*sinf(th);
    float pr = lre, pi = lim;
    long base = ((long)l*16 + (d>>4))*2048 + (d&15);
    for (int k = 0; k < 128; k++){
      g_lam[base + (long)k*16] = make_float2(pr, pi);
      float nr = pr*lre - pi*lim;
      float ni = pr*lim + pi*lre;
      pr = nr; pi = ni;
    }
    return;
  }
  {
    // item-embedding gather, 16 tokens per block
    int tok = (bi - 3074)*16 + (t>>4);
    int cg = t & 15;
    int id = ids[tok];
    const float* p = item_emb + (size_t)id*128 + cg*8;
    float4 x0 = *(const float4*)p;
    float4 x1 = *(const float4*)(p + 4);
    bf16x8 v;
    v[0]=f2bf(x0.x); v[1]=f2bf(x0.y); v[2]=f2bf(x0.z); v[3]=f2bf(x0.w);
    v[4]=f2bf(x1.x); v[5]=f2bf(x1.y); v[6]=f2bf(x1.z); v[7]=f2bf(x1.w);
    *(bf16x8*)((short*)g_cat + (long)(cg>>1)*SB16 + (long)tok*16 + (cg&1)*8) = v;
  }
}

// ---------------- MFMA GEMM body, BK=64, gl16 staging, half-swizzled LDS ----
// NSPLIT>1: 1-D grid of mtiles*NSPLIT blocks, XCD-affinity decode so all
// N-chunks of one M-tile land on the same XCD (A re-reads become L2 hits).
// Requires mtiles % 8 == 0 (bijective). NSPLIT==1: standard 2-D grid.
template<int TM, int ACT, int EPI, bool GATHER, bool COLSCALE, int NSPLIT=1>
__device__ __forceinline__ void mgemm_body(
    const short* __restrict__ A, const float* __restrict__ Af32, int ldaF,
    const short* __restrict__ W, long wBlk,
    const float* __restrict__ bias, const float* __restrict__ gamma,
    const int* __restrict__ gidx, short* __restrict__ C,
    long aBlk, int colOff, int K,
    const float* __restrict__ lnG, const float* __restrict__ lnB,
    float* __restrict__ outF)
{
  constexpr int ACH = TM*32;                 // bytes per 16-k A chunk
  __shared__ __align__(16) char lA[TM*128];
  __shared__ __align__(16) char lB[16384];
  constexpr int MF = (EPI==0) ? (TM/32) : 1;
  constexpr int NF = (EPI==0) ? 4 : 8;
  const int t = threadIdx.x;
  int m0, n0;
  if (NSPLIT == 1){
    m0 = blockIdx.x*TM; n0 = blockIdx.y*128;
  } else {
    int bid = blockIdx.x;
    int xcd = bid & 7, q = bid >> 3;
    int nn = q & (NSPLIT-1), s = q / NSPLIT;
    m0 = (8*s + xcd)*TM; n0 = nn*128;
  }
  const int lane = t & 63, wv = t >> 6;
  const int wr = (EPI==0)?(wv>>1):wv;
  const int wc = (EPI==0)?(wv&1):0;
  const int fr = lane & 15, fq = lane >> 4;
  const int rowB = (EPI==0) ? wr*(TM/2) : wv*16;
  const int colB = wc*64;
  const int lr2 = lane >> 1;
  const int h2 = (lane&1) ^ ((lane>>3)&1);         // pre-swizzled source half
  const int sx = ((fq&1) ^ ((fr>>2)&1)) << 4;      // swizzled read offset

  long gr0 = 0, gr1 = 0;
  if (GATHER){ gr0 = gidx[m0 + (t>>3)]; gr1 = gidx[m0 + (t>>3) + 32]; }

  f32x4 acc[MF][NF] = {};

  for (int k0 = 0; k0 < K; k0 += 64){
    if (TM == 128){
      #pragma unroll
      for (int cc = 0; cc < 4; cc++){
        const short* gp = A + (long)((k0>>4)+cc)*aBlk + (long)(m0 + wv*32 + lr2)*16 + h2*8;
        gl16(gp, lA + cc*4096 + wv*1024);
      }
      #pragma unroll
      for (int cc = 0; cc < 4; cc++){
        const short* gp = W + (long)((k0>>4)+cc)*wBlk + (long)(n0 + wv*32 + lr2)*16 + h2*8;
        gl16(gp, lB + cc*4096 + wv*1024);
      }
    } else {
      if (GATHER){
        #pragma unroll
        for (int rep = 0; rep < 2; rep++){
          int slot = t + rep*256;
          int row = slot>>3, cc = (slot>>1)&3, half = slot&1;
          int halfS = half ^ ((slot>>5)&1);          // swizzled LDS half
          long ar = rep ? gr1 : gr0;
          const float* p = Af32 + ar*(long)ldaF + k0 + cc*16 + half*8;
          float4 x0 = *(const float4*)p;
          float4 x1 = *(const float4*)(p + 4);
          bf16x8 v;
          v[0]=f2bf(x0.x); v[1]=f2bf(x0.y); v[2]=f2bf(x0.z); v[3]=f2bf(x0.w);
          v[4]=f2bf(x1.x); v[5]=f2bf(x1.y); v[6]=f2bf(x1.z); v[7]=f2bf(x1.w);
          *(bf16x8*)(lA + cc*2048 + row*32 + halfS*16) = v;
        }
      } else {
        #pragma unroll
        for (int p = 0; p < 2; p++){
          const short* gp = A + (long)((k0>>4)+wv)*aBlk + (long)(m0 + p*32 + lr2)*16 + h2*8;
          gl16(gp, lA + wv*2048 + p*1024);
        }
      }
      #pragma unroll
      for (int p = 0; p < 4; p++){
        const short* gp = W + (long)((k0>>4)+wv)*wBlk + (long)(n0 + p*32 + lr2)*16 + h2*8;
        gl16(gp, lB + wv*4096 + p*1024);
      }
    }
    __syncthreads();
    #pragma unroll
    for (int s = 0; s < 2; s++){
      const int cc = s*2 + (fq>>1);
      bf16x8 af[MF], bw[NF];
      #pragma unroll
      for (int m = 0; m < MF; m++)
        af[m] = *(const bf16x8*)(lA + cc*ACH + (rowB + m*16 + fr)*32 + sx);
      #pragma unroll
      for (int n = 0; n < NF; n++)
        bw[n] = *(const bf16x8*)(lB + cc*4096 + (colB + n*16 + fr)*32 + sx);
      #pragma unroll
      for (int m = 0; m < MF; m++)
        #pragma unroll
        for (int n = 0; n < NF; n++)
          acc[m][n] = __builtin_amdgcn_mfma_f32_16x16x32_bf16(af[m], bw[n], acc[m][n], 0, 0, 0);
    }
    __syncthreads();
  }

  if (EPI == 0){
    #pragma unroll
    for (int m = 0; m < MF; m++){
      #pragma unroll
      for (int j = 0; j < 4; j++){
        long row = m0 + rowB + m*16 + fq*4 + j;
        #pragma unroll
        for (int n = 0; n < NF; n++){
          int colL = n0 + colB + n*16 + fr;
          float v = acc[m][n][j] + bias[colL];
          if (COLSCALE) v *= gamma[colL];
          if (ACT == 1) v = 0.5f * v * (1.0f + erff(v * 0.70710678118654752f));
          int colS = colL + colOff;
          C[(long)(colS>>4)*SB16 + row*16 + (colS&15)] = f2bf(v);
        }
      }
    }
  } else {
    #pragma unroll
    for (int j = 0; j < 4; j++){
      int rt = rowB + fq*4 + j;
      long tok = m0 + rt;
      float vv[NF];
      float s1 = 0.f, s2 = 0.f;
      #pragma unroll
      for (int n = 0; n < NF; n++){
        int col = n*16 + fr;
        float v = acc[0][n][j] + bias[col];
        if (EPI == 2){
          v = 1.0f / (1.0f + expf(-v));
          float idv = bf2f(((const short*)g_cat)[(long)n*SB16 + tok*16 + fr]);
          float lmv = bf2f(((const short*)g_cat)[(long)(n+8)*SB16 + tok*16 + fr]);
          v = v*idv + (1.0f - v)*lmv;
        } else {
          v += bf2f(((const short*)g_xb)[(long)n*SB16 + tok*16 + fr]);
        }
        vv[n] = v; s1 += v; s2 += v*v;
      }
      #pragma unroll
      for (int off = 1; off < 16; off <<= 1){
        s1 += __shfl_xor(s1, off); s2 += __shfl_xor(s2, off);
      }
      float mu = s1 * (1.f/128.f);
      float var = s2 * (1.f/128.f) - mu*mu;
      float rstd = rsqrtf(var + 1e-12f);
      #pragma unroll
      for (int n = 0; n < NF; n++){
        int col = n*16 + fr;
        float o = (vv[n] - mu)*rstd*lnG[col] + lnB[col];
        if (EPI == 3)
          outF[tok*128 + col] = o;
        else
          ((short*)g_xb)[(long)n*SB16 + tok*16 + fr] = f2bf(o);
      }
    }
  }
}

// ---------------- named single-GEMM wrappers --------------------------------
__global__ __launch_bounds__(256) void kg_llm(const float* llm_emb, const float* b_map, const int* ids){
  mgemm_body<64,0,0,true,false>(nullptr, llm_emb, 768, (const short*)g_Wmap, 128L*16,
                                b_map, nullptr, ids, (short*)g_cat, 0, 128, 768, nullptr, nullptr, nullptr);
}
__global__ __launch_bounds__(256) void kg_g1(const float* bg1){
  mgemm_body<64,1,0,false,false,2>((const short*)g_cat, nullptr, 0, (const short*)g_Wg1, 256L*16,
                                   bg1, nullptr, nullptr, (short*)g_g1, SB16, 0, 256, nullptr, nullptr, nullptr);
}
__global__ __launch_bounds__(256) void kg_gate(const float* bg2, const float* ln0g, const float* ln0b){
  mgemm_body<64,0,2,false,false>((const short*)g_g1, nullptr, 0, (const short*)g_Wg2, 128L*16,
                                 bg2, nullptr, nullptr, nullptr, SB16, 0, 256, ln0g, ln0b, nullptr);
}
__global__ __launch_bounds__(256) void kg_h(int l){
  mgemm_body<128,0,0,false,true,4>((const short*)g_xb, nullptr, 0,
                                   (const short*)g_Wincat + (long)l*65536, 512L*16,
                                   g_bincat + l*512, g_gamma2 + l*512, nullptr, (short*)g_h,
                                   SB16, 0, 128, nullptr, nullptr, nullptr);
}
__global__ __launch_bounds__(256) void kg_out(int l, const float* bout, const float* g, const float* b){
  mgemm_body<64,0,1,false,false>((const short*)g_h, nullptr, 0,
                                 (const short*)g_Woutcat + (long)l*65536, 128L*16,
                                 bout, nullptr, nullptr, nullptr, SB16, 0, 512, g, b, nullptr);
}
__global__ __launch_bounds__(256) void kg_ff1(int l, const float* bff1){
  mgemm_body<128,1,0,false,false,4>((const short*)g_xb, nullptr, 0,
                                    (const short*)g_Wff1 + (long)l*65536, 512L*16,
                                    bff1, nullptr, nullptr, (short*)g_ffh, SB16, 0, 128, nullptr, nullptr, nullptr);
}
__global__ __launch_bounds__(256) void kg_ff2(int l, const float* bff2, const float* g, const float* b){
  mgemm_body<64,0,1,false,false>((const short*)g_ffh, nullptr, 0,
                                 (const short*)g_Wff2 + (long)l*65536, 128L*16,
                                 bff2, nullptr, nullptr, nullptr, SB16, 0, 512, g, b, nullptr);
}
__global__ __launch_bounds__(256) void kg_ff2o(int l, const float* bff2, const float* g, const float* b,
                                               float* outF){
  mgemm_body<64,0,3,false,false>((const short*)g_ffh, nullptr, 0,
                                 (const short*)g_Wff2 + (long)l*65536, 128L*16,
                                 bff2, nullptr, nullptr, nullptr, SB16, 0, 512, g, b, outF);
}

// ---------------- blocked LRU scan (r6 LDS version, proven) -----------------
__global__ __launch_bounds__(256) void k_scan(int l){
  __shared__ __align__(16) float sre[CL*16];
  __shared__ __align__(16) float sim[CL*16];
  __shared__ float smask[CL];
  int b = blockIdx.y, ch = blockIdx.x;  // ch 0..15
  int tid = threadIdx.x;
  short* Hre = (short*)g_h + (long)ch*SB16 + (long)b*CS*16;
  short* Him = (short*)g_h + (long)(ch+16)*SB16 + (long)b*CS*16;
  smask[tid] = g_mask[b*CL + tid];
  for (int q = tid; q < 224; q += 256){    // zero pad rows 0..55
    ((float4*)sre)[q] = make_float4(0.f,0.f,0.f,0.f);
    ((float4*)sim)[q] = make_float4(0.f,0.f,0.f,0.f);
  }
  for (int q = tid; q < 400; q += 256){    // 200 tokens * 16 / 8
    bf16x8 r8 = ((const bf16x8*)Hre)[q];
    bf16x8 i8 = ((const bf16x8*)Him)[q];
    int base = 896 + q*8;
    #pragma unroll
    for (int k = 0; k < 8; k++){ sre[base+k] = bf2f(r8[k]); sim[base+k] = bf2f(i8[k]); }
  }
  __syncthreads();
  const float2* lam = g_lam + ((long)l*16 + ch)*2048;
  const int dl = tid & 15, u0 = tid >> 4;
  for (int i = 1; i <= 8; i++){
    int hl = 1 << (i-1);
    #pragma unroll
    for (int k = 0; k < 8; k++){
      int u = u0 + k*16;
      int blkI = u >> (i-1), j = u & (hl-1);
      int p = (blkI << i) + hl - 1;
      int tt = p + 1 + j;
      float mv = smask[p];
      float2 L = lam[j*16 + dl];
      float hr = sre[p*16+dl], hi = sim[p*16+dl];
      sre[tt*16+dl] += (L.x*hr - L.y*hi) * mv;
      sim[tt*16+dl] += (L.x*hi + L.y*hr) * mv;
    }
    __syncthreads();
  }
  for (int q = tid; q < 400; q += 256){
    int base = 896 + q*8;
    bf16x8 r8, i8;
    #pragma unroll
    for (int k = 0; k < 8; k++){ r8[k] = f2bf(sre[base+k]); i8[k] = f2bf(sim[base+k]); }
    ((bf16x8*)Hre)[q] = r8;
    ((bf16x8*)Him)[q] = i8;
  }
}

// ---------------------------------------------------------------------------
extern "C" void kernel_launch(void* const* d_in, const int* in_sizes, int n_in,
                              void* d_out, int out_size, void* d_ws, size_t ws_size,
                              hipStream_t stream) {
  const int*   ids       = (const int*)  d_in[0];
  const float* item_emb  = (const float*)d_in[1];
  const float* llm_emb   = (const float*)d_in[2];
  const float* W_map     = (const float*)d_in[3];
  const float* b_map     = (const float*)d_in[4];
  const float* Wg1       = (const float*)d_in[5];
  const float* bg1       = (const float*)d_in[6];
  const float* Wg2       = (const float*)d_in[7];
  const float* bg2       = (const float*)d_in[8];
  const float* ln0_g     = (const float*)d_in[9];
  const float* ln0_b     = (const float*)d_in[10];
  const float* params_log= (const float*)d_in[11];
  const float* Win_re    = (const float*)d_in[12];
  const float* Win_im    = (const float*)d_in[13];
  const float* bin_re    = (const float*)d_in[14];
  const float* bin_im    = (const float*)d_in[15];
  const float* Wout_re   = (const float*)d_in[16];
  const float* Wout_im   = (const float*)d_in[17];
  const float* bout_re   = (const float*)d_in[18];
  const float* ln1_g     = (const float*)d_in[20];
  const float* ln1_b     = (const float*)d_in[21];
  const float* Wff1      = (const float*)d_in[22];
  const float* bff1      = (const float*)d_in[23];
  const float* Wff2      = (const float*)d_in[24];
  const float* bff2      = (const float*)d_in[25];
  const float* ln2_g     = (const float*)d_in[26];
  const float* ln2_b     = (const float*)d_in[27];
  float* out = (float*)d_out;

  dim3 blk(256);

  k_setup<<<6274, blk, 0, stream>>>(W_map, Wg1, Wg2, Win_re, Win_im,
                                    Wout_re, Wout_im, Wff1, Wff2,
                                    ids, params_log, bin_re, bin_im, item_emb);

  kg_llm <<<dim3(800,1), blk, 0, stream>>>(llm_emb, b_map, ids);
  kg_g1  <<<1600, blk, 0, stream>>>(bg1);
  kg_gate<<<dim3(800,1), blk, 0, stream>>>(bg2, ln0_g, ln0_b);

  for (int l = 0; l < 2; l++){
    kg_h  <<<1600, blk, 0, stream>>>(l);
    k_scan<<<dim3(16,CB), blk, 0, stream>>>(l);
    kg_out<<<dim3(800,1), blk, 0, stream>>>(l, bout_re + l*128, ln1_g + l*128, ln1_b + l*128);
    kg_ff1<<<1600, blk, 0, stream>>>(l, bff1 + l*512);
    if (l == 0)
      kg_ff2 <<<dim3(800,1), blk, 0, stream>>>(l, bff2 + l*128, ln2_g + l*128, ln2_b + l*128);
    else
      kg_ff2o<<<dim3(800,1), blk, 0, stream>>>(l, bff2 + l*128, ln2_g + l*128, ln2_b + l*128, out);
  }
}